// Round 5
// baseline (835.701 us; speedup 1.0000x reference)
//
#include <hip/hip_runtime.h>
#include <hip/hip_bf16.h>
#include <math.h>

#define N_NODES 100000
#define N_EDGES 1600000
#define ET (N_EDGES + N_NODES)   // edges + self-loops
#define N_GRAPHS 512
#define NEG_SLOPE 0.2f
#define SCAN_BS 1024
#define NB_SCAN ((N_NODES + SCAN_BS - 1) / SCAN_BS)   // 98

__device__ __forceinline__ void atomAddF(float* p, float v) { unsafeAtomicAdd(p, v); }
__device__ __forceinline__ float lrelu(float v) { return v >= 0.f ? v : NEG_SLOPE * v; }

// bf16 helpers (RNE round)
__device__ __forceinline__ unsigned short f2bf(float f) {
    unsigned int u = __float_as_uint(f);
    u += 0x7FFFu + ((u >> 16) & 1u);
    return (unsigned short)(u >> 16);
}
__device__ __forceinline__ float bf2f(unsigned short s) { return __uint_as_float(((unsigned int)s) << 16); }
__device__ __forceinline__ float bflo(unsigned int p) { return __uint_as_float(p << 16); }
__device__ __forceinline__ float bfhi(unsigned int p) { return __uint_as_float(p & 0xFFFF0000u); }

// ---- init ----------------------------------------------------------------
__global__ void k_out_init(float* __restrict__ out, const float* __restrict__ bg) {
    int i = blockIdx.x * blockDim.x + threadIdx.x;
    if (i < N_GRAPHS) out[i] = bg[0];
}

// ---- CSR build -----------------------------------------------------------
__global__ __launch_bounds__(256) void k_deg(const int* __restrict__ ei, int* __restrict__ deg) {
    int e = blockIdx.x * 256 + threadIdx.x;
    if (e >= ET) return;
    int dst = (e < N_EDGES) ? ei[N_EDGES + e] : (e - N_EDGES);
    atomicAdd(deg + dst, 1);
}

__global__ __launch_bounds__(SCAN_BS) void k_scan1(const int* __restrict__ deg,
                                                   int* __restrict__ excl, int* __restrict__ bsum) {
    __shared__ int sh[SCAN_BS];
    const int t = threadIdx.x;
    const int i = blockIdx.x * SCAN_BS + t;
    int v = (i < N_NODES) ? deg[i] : 0;
    sh[t] = v;
    __syncthreads();
    for (int off = 1; off < SCAN_BS; off <<= 1) {
        int a = (t >= off) ? sh[t - off] : 0;
        __syncthreads();
        sh[t] += a;
        __syncthreads();
    }
    if (i < N_NODES) excl[i] = sh[t] - v;
    if (t == SCAN_BS - 1) bsum[blockIdx.x] = sh[t];
}

__global__ __launch_bounds__(128) void k_scan2(int* __restrict__ bsum) {
    __shared__ int sh[128];
    const int t = threadIdx.x;
    int v = (t < NB_SCAN) ? bsum[t] : 0;
    sh[t] = v;
    __syncthreads();
    for (int off = 1; off < 128; off <<= 1) {
        int a = (t >= off) ? sh[t - off] : 0;
        __syncthreads();
        sh[t] += a;
        __syncthreads();
    }
    if (t < NB_SCAN) bsum[t] = sh[t] - v;   // exclusive
}

__global__ __launch_bounds__(256) void k_scan3(const int* __restrict__ excl, const int* __restrict__ bsum,
                                               int* __restrict__ rowptr, int* __restrict__ cursor) {
    int i = blockIdx.x * 256 + threadIdx.x;
    if (i < N_NODES) {
        int r = excl[i] + bsum[i / SCAN_BS];
        rowptr[i] = r;
        cursor[i] = r;
    }
    if (i == 0) rowptr[N_NODES] = ET;
}

__global__ __launch_bounds__(256) void k_fill(const int* __restrict__ ei,
                                              int* __restrict__ cursor, int* __restrict__ ecol) {
    int e = blockIdx.x * 256 + threadIdx.x;
    if (e >= ET) return;
    int src, dst;
    if (e < N_EDGES) { src = ei[e]; dst = ei[N_EDGES + e]; }
    else             { src = dst = e - N_EDGES; }
    int slot = atomicAdd(cursor + dst, 1);
    ecol[slot] = src;
}

// ---- conv1 features ------------------------------------------------------
__global__ __launch_bounds__(256) void k_feat1(
    const float* __restrict__ x, const float* __restrict__ W1,
    const float* __restrict__ as1, const float* __restrict__ ad1,
    unsigned short* __restrict__ h1p, float* __restrict__ a1s, float* __restrict__ a1d)
{
    __shared__ float xs[4][76];
    const int g = threadIdx.x >> 6;
    const int c = threadIdx.x & 63;
    const int n = blockIdx.x * 4 + g;  // grid = N/4 exactly
    const float* xr = x + (long)n * 75;
    xs[g][c] = xr[c];
    if (c < 11) xs[g][64 + c] = xr[64 + c];
    __syncthreads();
    float h = 0.f;
    #pragma unroll
    for (int k = 0; k < 75; ++k) h += xs[g][k] * W1[k * 64 + c];
    h1p[(long)n * 64 + c] = f2bf(h);
    const int head = c >> 3, lane = c & 7;
    float vs = h * as1[c];
    float vd = h * ad1[c];
    #pragma unroll
    for (int off = 1; off < 8; off <<= 1) {
        vs += __shfl_xor(vs, off, 64);
        vd += __shfl_xor(vd, off, 64);
    }
    if (lane == 0) { a1s[n * 8 + head] = vs; a1d[n * 8 + head] = vd; }
}

// ---- conv1 attention pass: ee1[j*8+h] (bf16), dinv1[dst*8+h] -------------
// 8 edge-groups x 8 heads: lane = 8*g + l handles edge beg+g (+8...), head l
__global__ __launch_bounds__(256) void k_att1(
    const int* __restrict__ rowptr, const int* __restrict__ ecol,
    const float* __restrict__ a1s, const float* __restrict__ a1d,
    unsigned short* __restrict__ ee1, float* __restrict__ dinv1)
{
    const int dst  = blockIdx.x * 4 + (threadIdx.x >> 6);  // grid = N/4
    const int lane = threadIdx.x & 63;
    const int g = lane >> 3;
    const int l = lane & 7;
    const int beg = rowptr[dst], end = rowptr[dst + 1];
    const float adh = a1d[(long)dst * 8 + l];
    float den = 0.f;
    for (int j = beg + g; j < end; j += 8) {
        int s = ecol[j];
        float ee = __expf(lrelu(a1s[(long)s * 8 + l] + adh));
        den += ee;
        ee1[(long)j * 8 + l] = f2bf(ee);
    }
    #pragma unroll
    for (int off = 8; off <= 32; off <<= 1) den += __shfl_xor(den, off, 64);
    if (g == 0) dinv1[(long)dst * 8 + l] = 1.f / den;
}

// ---- conv1 aggregation: 8 edge-groups x 8 channel-lanes ------------------
// lane = 8*g + l: edges beg+g (+8...); head l, channels 8l..8l+7 (dwordx4)
__global__ __launch_bounds__(256) void k_gat1(
    const int* __restrict__ rowptr, const int* __restrict__ ecol,
    const unsigned short* __restrict__ ee1, const float* __restrict__ dinv1,
    const unsigned short* __restrict__ h1p, const float* __restrict__ bias1,
    float* __restrict__ x2)
{
    const int dst  = blockIdx.x * 4 + (threadIdx.x >> 6);  // grid = N/4
    const int lane = threadIdx.x & 63;
    const int g = lane >> 3;
    const int l = lane & 7;
    const int beg = rowptr[dst], end = rowptr[dst + 1];

    float acc[8] = {0.f,0.f,0.f,0.f,0.f,0.f,0.f,0.f};

    int j = beg + g;
    bool v = (j < end);
    int s = v ? ecol[j] : 0;
    float w = v ? bf2f(ee1[(long)j * 8 + l]) : 0.f;
    uint4 pv = *(const uint4*)(h1p + (long)s * 64 + l * 8);

    for (int j0 = beg; j0 < end; j0 += 8) {
        int jn = j + 8;
        bool vn = (jn < end);
        int sn = vn ? ecol[jn] : 0;
        float wn = vn ? bf2f(ee1[(long)jn * 8 + l]) : 0.f;
        uint4 pvn = *(const uint4*)(h1p + (long)sn * 64 + l * 8);
        acc[0] += w * bflo(pv.x); acc[1] += w * bfhi(pv.x);
        acc[2] += w * bflo(pv.y); acc[3] += w * bfhi(pv.y);
        acc[4] += w * bflo(pv.z); acc[5] += w * bfhi(pv.z);
        acc[6] += w * bflo(pv.w); acc[7] += w * bfhi(pv.w);
        j = jn; v = vn; s = sn; w = wn; pv = pvn;
    }

    #pragma unroll
    for (int off = 8; off <= 32; off <<= 1) {
        #pragma unroll
        for (int k = 0; k < 8; ++k) acc[k] += __shfl_xor(acc[k], off, 64);
    }

    if (g == 0) {
        const float inv = dinv1[(long)dst * 8 + l];
        float o[8];
        #pragma unroll
        for (int k = 0; k < 8; ++k) {
            float vv = acc[k] * inv + bias1[l * 8 + k];
            o[k] = vv > 0.f ? vv : (__expf(vv) - 1.f);
        }
        float4* xo = (float4*)(x2 + (long)dst * 64 + l * 8);
        xo[0] = make_float4(o[0], o[1], o[2], o[3]);
        xo[1] = make_float4(o[4], o[5], o[6], o[7]);
    }
}

// ---- conv2 features ------------------------------------------------------
__global__ __launch_bounds__(256) void k_feat2(
    const float* __restrict__ x2, const float* __restrict__ W2,
    const float* __restrict__ as2, const float* __restrict__ ad2,
    unsigned int* __restrict__ h2p, float* __restrict__ a2s, float* __restrict__ a2d)
{
    __shared__ float xs[4][64];
    const int g = threadIdx.x >> 6;
    const int c = threadIdx.x & 63;
    const int n = blockIdx.x * 4 + g;   // grid = N/4 exactly
    xs[g][c] = x2[(long)n * 64 + c];
    __syncthreads();
    float hlo = 0.f, hhi = 0.f;
    #pragma unroll
    for (int k = 0; k < 64; ++k) {
        float xv = xs[g][k];
        hlo += xv * W2[k * 128 + c];
        hhi += xv * W2[k * 128 + c + 64];
    }
    h2p[(long)n * 64 + c] = (unsigned int)f2bf(hlo) | ((unsigned int)f2bf(hhi) << 16);
    float vs = hlo * as2[c] + hhi * as2[c + 64];
    float vd = hlo * ad2[c] + hhi * ad2[c + 64];
    #pragma unroll
    for (int off = 1; off < 64; off <<= 1) {
        vs += __shfl_xor(vs, off, 64);
        vd += __shfl_xor(vd, off, 64);
    }
    if (c == 0) { a2s[n] = vs; a2d[n] = vd; }
}

// ---- conv2 attention pass: lane = edge (64-way MLP) ----------------------
__global__ __launch_bounds__(256) void k_att2(
    const int* __restrict__ rowptr, const int* __restrict__ ecol,
    const float* __restrict__ a2s, const float* __restrict__ a2d,
    float* __restrict__ ee2, float* __restrict__ dinv2)
{
    const int dst  = blockIdx.x * 4 + (threadIdx.x >> 6);  // grid = N/4
    const int lane = threadIdx.x & 63;
    const int beg = rowptr[dst], end = rowptr[dst + 1];
    const float adv = a2d[dst];
    float den = 0.f;
    for (int j = beg + lane; j < end; j += 64) {
        float ee = __expf(lrelu(a2s[ecol[j]] + adv));
        den += ee;
        ee2[j] = ee;
    }
    #pragma unroll
    for (int off = 1; off < 64; off <<= 1) den += __shfl_xor(den, off, 64);
    if (lane == 0) dinv2[dst] = 1.f / den;
}

// ---- conv2 aggregation + pool + linear: 8 edge-groups x 8 lanes ----------
// lane = 8*g + l: edges beg+g (+8...); lane covers packed uints l*8..l*8+7
// (channels l*8..l*8+7 and +64), two dwordx4 per edge.
__global__ __launch_bounds__(256) void k_gat2(
    const int* __restrict__ rowptr, const int* __restrict__ ecol,
    const float* __restrict__ ee2, const float* __restrict__ dinv2,
    const unsigned int* __restrict__ h2p, const float* __restrict__ bias2,
    const float* __restrict__ Wg, const int* __restrict__ batch,
    float* __restrict__ out)
{
    const int dst  = blockIdx.x * 4 + (threadIdx.x >> 6);  // grid = N/4
    const int lane = threadIdx.x & 63;
    const int g = lane >> 3;
    const int l = lane & 7;
    const int beg = rowptr[dst], end = rowptr[dst + 1];

    float acc[16];
    #pragma unroll
    for (int k = 0; k < 16; ++k) acc[k] = 0.f;

    int j = beg + g;
    bool v = (j < end);
    int s = v ? ecol[j] : 0;
    float w = v ? ee2[j] : 0.f;
    const uint4* hr = (const uint4*)(h2p + (long)s * 64 + l * 8);
    uint4 pa = hr[0], pb = hr[1];

    for (int j0 = beg; j0 < end; j0 += 8) {
        int jn = j + 8;
        bool vn = (jn < end);
        int sn = vn ? ecol[jn] : 0;
        float wn = vn ? ee2[jn] : 0.f;
        const uint4* hrn = (const uint4*)(h2p + (long)sn * 64 + l * 8);
        uint4 pan = hrn[0], pbn = hrn[1];
        acc[0]  += w * bflo(pa.x); acc[1]  += w * bfhi(pa.x);
        acc[2]  += w * bflo(pa.y); acc[3]  += w * bfhi(pa.y);
        acc[4]  += w * bflo(pa.z); acc[5]  += w * bfhi(pa.z);
        acc[6]  += w * bflo(pa.w); acc[7]  += w * bfhi(pa.w);
        acc[8]  += w * bflo(pb.x); acc[9]  += w * bfhi(pb.x);
        acc[10] += w * bflo(pb.y); acc[11] += w * bfhi(pb.y);
        acc[12] += w * bflo(pb.z); acc[13] += w * bfhi(pb.z);
        acc[14] += w * bflo(pb.w); acc[15] += w * bfhi(pb.w);
        j = jn; v = vn; s = sn; w = wn; pa = pan; pb = pbn;
    }

    // per-lane partial dot with Wg; uint index w = l*8+t -> ch w and w+64
    float dot = 0.f;
    #pragma unroll
    for (int t = 0; t < 4; ++t) {
        dot += acc[2 * t]     * Wg[l * 8 + t];
        dot += acc[2 * t + 1] * Wg[l * 8 + t + 64];
        dot += acc[8 + 2 * t] * Wg[l * 8 + 4 + t];
        dot += acc[9 + 2 * t] * Wg[l * 8 + 4 + t + 64];
    }
    float bc = bias2[lane] * Wg[lane] + bias2[lane + 64] * Wg[lane + 64];
    #pragma unroll
    for (int off = 1; off < 64; off <<= 1) {
        dot += __shfl_xor(dot, off, 64);
        bc  += __shfl_xor(bc,  off, 64);
    }
    if (lane == 0) atomAddF(out + batch[dst], dot * dinv2[dst] + bc);
}

extern "C" void kernel_launch(void* const* d_in, const int* in_sizes, int n_in,
                              void* d_out, int out_size, void* d_ws, size_t ws_size,
                              hipStream_t stream) {
    (void)in_sizes; (void)n_in; (void)out_size; (void)ws_size;
    const float* x     = (const float*)d_in[0];
    const int*   ei    = (const int*)d_in[1];
    const int*   batch = (const int*)d_in[2];
    const float* W1    = (const float*)d_in[3];
    const float* as1   = (const float*)d_in[4];
    const float* ad1   = (const float*)d_in[5];
    const float* b1    = (const float*)d_in[6];
    const float* W2    = (const float*)d_in[7];
    const float* as2   = (const float*)d_in[8];
    const float* ad2   = (const float*)d_in[9];
    const float* b2    = (const float*)d_in[10];
    const float* Wg    = (const float*)d_in[11];
    const float* bg    = (const float*)d_in[12];
    float* out = (float*)d_out;

    // ---- workspace layout (all chunks 16-B aligned; total ~118 MB) ----
    const long N = N_NODES;
    char* p = (char*)d_ws;
    int* deg    = (int*)p;              p += (N)      * sizeof(int);
    int* excl   = (int*)p;              p += (N)      * sizeof(int);
    int* rowptr = (int*)p;              p += (N + 4)  * sizeof(int);   // +4: keep 16B align
    int* cursor = (int*)p;              p += (N)      * sizeof(int);
    int* bsum   = (int*)p;              p += 128      * sizeof(int);
    int* ecol   = (int*)p;              p += (long)ET * sizeof(int);
    unsigned short* h1p = (unsigned short*)p; p += N * 64 * sizeof(unsigned short);
    unsigned int*   h2p = (unsigned int*)p;   p += N * 64 * sizeof(unsigned int);
    unsigned short* ee1 = (unsigned short*)p; p += (long)ET * 8 * sizeof(unsigned short);
    float* dinv1 = (float*)p;           p += N * 8    * sizeof(float);
    float* ee2  = (float*)p;            p += (long)ET * sizeof(float);
    float* dinv2 = (float*)p;           p += N        * sizeof(float);
    float* a1s  = (float*)p;            p += N * 8    * sizeof(float);
    float* a1d  = (float*)p;            p += N * 8    * sizeof(float);
    float* x2   = (float*)p;            p += N * 64   * sizeof(float);
    float* a2s  = (float*)p;            p += N        * sizeof(float);
    float* a2d  = (float*)p;            p += N        * sizeof(float);

    // ---- CSR build ----
    hipMemsetAsync(deg, 0, N * sizeof(int), stream);
    k_deg  <<<(ET + 255) / 256, 256, 0, stream>>>(ei, deg);
    k_scan1<<<NB_SCAN, SCAN_BS, 0, stream>>>(deg, excl, bsum);
    k_scan2<<<1, 128, 0, stream>>>(bsum);
    k_scan3<<<(N_NODES + 255) / 256, 256, 0, stream>>>(excl, bsum, rowptr, cursor);
    k_fill <<<(ET + 255) / 256, 256, 0, stream>>>(ei, cursor, ecol);

    // ---- conv1 ----
    k_feat1<<<N_NODES / 4, 256, 0, stream>>>(x, W1, as1, ad1, h1p, a1s, a1d);
    k_att1 <<<N_NODES / 4, 256, 0, stream>>>(rowptr, ecol, a1s, a1d, ee1, dinv1);
    k_gat1 <<<N_NODES / 4, 256, 0, stream>>>(rowptr, ecol, ee1, dinv1, h1p, b1, x2);

    // ---- conv2 + pool + linear ----
    k_feat2<<<N_NODES / 4, 256, 0, stream>>>(x2, W2, as2, ad2, h2p, a2s, a2d);
    k_att2 <<<N_NODES / 4, 256, 0, stream>>>(rowptr, ecol, a2s, a2d, ee2, dinv2);
    k_out_init<<<2, 256, 0, stream>>>(out, bg);
    k_gat2 <<<N_NODES / 4, 256, 0, stream>>>(rowptr, ecol, ee2, dinv2, h2p, b2, Wg, batch, out);
}

// Round 6
// 623.189 us; speedup vs baseline: 1.3410x; 1.3410x over previous
//
#include <hip/hip_runtime.h>
#include <hip/hip_bf16.h>
#include <math.h>

#define N_NODES 100000
#define N_EDGES 1600000
#define ET (N_EDGES + N_NODES)   // edges + self-loops
#define N_GRAPHS 512
#define NEG_SLOPE 0.2f
#define SCAN_BS 1024
#define NB_SCAN ((N_NODES + SCAN_BS - 1) / SCAN_BS)   // 98
#define E_CAP 64   // per-dst LDS edge cap; deg>E_CAP handled by inline fallback

__device__ __forceinline__ void atomAddF(float* p, float v) { unsafeAtomicAdd(p, v); }
__device__ __forceinline__ float lrelu(float v) { return v >= 0.f ? v : NEG_SLOPE * v; }

// bf16 helpers (RNE round)
__device__ __forceinline__ unsigned short f2bf(float f) {
    unsigned int u = __float_as_uint(f);
    u += 0x7FFFu + ((u >> 16) & 1u);
    return (unsigned short)(u >> 16);
}
__device__ __forceinline__ float bflo(unsigned int p) { return __uint_as_float(p << 16); }
__device__ __forceinline__ float bfhi(unsigned int p) { return __uint_as_float(p & 0xFFFF0000u); }

// ---- init ----------------------------------------------------------------
__global__ void k_out_init(float* __restrict__ out, const float* __restrict__ bg) {
    int i = blockIdx.x * blockDim.x + threadIdx.x;
    if (i < N_GRAPHS) out[i] = bg[0];
}

// ---- CSR build -----------------------------------------------------------
__global__ __launch_bounds__(256) void k_deg(const int* __restrict__ ei, int* __restrict__ deg) {
    int e = blockIdx.x * 256 + threadIdx.x;
    if (e >= ET) return;
    int dst = (e < N_EDGES) ? ei[N_EDGES + e] : (e - N_EDGES);
    atomicAdd(deg + dst, 1);
}

__global__ __launch_bounds__(SCAN_BS) void k_scan1(const int* __restrict__ deg,
                                                   int* __restrict__ excl, int* __restrict__ bsum) {
    __shared__ int sh[SCAN_BS];
    const int t = threadIdx.x;
    const int i = blockIdx.x * SCAN_BS + t;
    int v = (i < N_NODES) ? deg[i] : 0;
    sh[t] = v;
    __syncthreads();
    for (int off = 1; off < SCAN_BS; off <<= 1) {
        int a = (t >= off) ? sh[t - off] : 0;
        __syncthreads();
        sh[t] += a;
        __syncthreads();
    }
    if (i < N_NODES) excl[i] = sh[t] - v;
    if (t == SCAN_BS - 1) bsum[blockIdx.x] = sh[t];
}

__global__ __launch_bounds__(128) void k_scan2(int* __restrict__ bsum) {
    __shared__ int sh[128];
    const int t = threadIdx.x;
    int v = (t < NB_SCAN) ? bsum[t] : 0;
    sh[t] = v;
    __syncthreads();
    for (int off = 1; off < 128; off <<= 1) {
        int a = (t >= off) ? sh[t - off] : 0;
        __syncthreads();
        sh[t] += a;
        __syncthreads();
    }
    if (t < NB_SCAN) bsum[t] = sh[t] - v;   // exclusive
}

__global__ __launch_bounds__(256) void k_scan3(const int* __restrict__ excl, const int* __restrict__ bsum,
                                               int* __restrict__ rowptr, int* __restrict__ cursor) {
    int i = blockIdx.x * 256 + threadIdx.x;
    if (i < N_NODES) {
        int r = excl[i] + bsum[i / SCAN_BS];
        rowptr[i] = r;
        cursor[i] = r;
    }
    if (i == 0) rowptr[N_NODES] = ET;
}

__global__ __launch_bounds__(256) void k_fill(const int* __restrict__ ei,
                                              int* __restrict__ cursor, int* __restrict__ ecol) {
    int e = blockIdx.x * 256 + threadIdx.x;
    if (e >= ET) return;
    int src, dst;
    if (e < N_EDGES) { src = ei[e]; dst = ei[N_EDGES + e]; }
    else             { src = dst = e - N_EDGES; }
    int slot = atomicAdd(cursor + dst, 1);
    ecol[slot] = src;
}

// ---- precompute wv = {W2@Wg, W2@as2^T, W2@ad2^T} : 3 x 64 floats ---------
__global__ __launch_bounds__(256) void k_wv(
    const float* __restrict__ W2, const float* __restrict__ as2,
    const float* __restrict__ ad2, const float* __restrict__ Wg,
    float* __restrict__ wv)
{
    int i = threadIdx.x;
    if (i >= 192) return;
    int c = i & 63, which = i >> 6;
    const float* v = (which == 0) ? Wg : ((which == 1) ? as2 : ad2);
    float s = 0.f;
    #pragma unroll
    for (int t = 0; t < 128; ++t) s += W2[c * 128 + t] * v[t];
    wv[which * 64 + c] = s;
}

// ---- conv1 features: h1p = bf16(x@W1) [N,64]; a1s/a1d fp32 [N,8] ---------
__global__ __launch_bounds__(256) void k_feat1(
    const float* __restrict__ x, const float* __restrict__ W1,
    const float* __restrict__ as1, const float* __restrict__ ad1,
    unsigned short* __restrict__ h1p, float* __restrict__ a1s, float* __restrict__ a1d)
{
    __shared__ float xs[4][76];
    const int g = threadIdx.x >> 6;
    const int c = threadIdx.x & 63;
    const int n = blockIdx.x * 4 + g;  // grid = N/4 exactly
    const float* xr = x + (long)n * 75;
    xs[g][c] = xr[c];
    if (c < 11) xs[g][64 + c] = xr[64 + c];
    __syncthreads();
    float h = 0.f;
    #pragma unroll
    for (int k = 0; k < 75; ++k) h += xs[g][k] * W1[k * 64 + c];
    h1p[(long)n * 64 + c] = f2bf(h);
    const int head = c >> 3, lane = c & 7;
    float vs = h * as1[c];
    float vd = h * ad1[c];
    #pragma unroll
    for (int off = 1; off < 8; off <<= 1) {
        vs += __shfl_xor(vs, off, 64);
        vd += __shfl_xor(vd, off, 64);
    }
    if (lane == 0) { a1s[n * 8 + head] = vs; a1d[n * 8 + head] = vd; }
}

// ---- conv1 gather, fully fused:
//   phase 1: ee per (edge, head) -> LDS (8 edges x 8 heads per iter), den
//   phase 2: aggregation (8 edge-groups x 8 channel-lanes, pipelined)
//   epilogue: x2 = elu(acc/den + b1) kept in registers; project onto the 3
//             precomputed vectors -> sg2 = {a2s, g2}, a2d.  x2 never stored.
__global__ __launch_bounds__(256) void k_gat1(
    const int* __restrict__ rowptr, const int* __restrict__ ecol,
    const float* __restrict__ a1s, const float* __restrict__ a1d,
    const unsigned short* __restrict__ h1p, const float* __restrict__ bias1,
    const float* __restrict__ wv,
    float2* __restrict__ sg2, float* __restrict__ a2dv)
{
    __shared__ float sh_ee[4][E_CAP][8];   // [slot][edge][head] - conflict-free
    __shared__ int   sh_s[4][E_CAP];
    const int slot = threadIdx.x >> 6;
    const int dst  = blockIdx.x * 4 + slot;  // grid = N/4 exactly
    const int lane = threadIdx.x & 63;
    const int g = lane >> 3;     // edge-group
    const int l = lane & 7;      // head (phase1) / head+channel-block (phase2)
    const int beg = rowptr[dst], end = rowptr[dst + 1];
    const float adh = a1d[(long)dst * 8 + l];

    // ---- phase 1: attention weights (all edges, incl. beyond E_CAP for den)
    float den = 0.f;
    for (int j = beg + g; j < end; j += 8) {
        int s = ecol[j];
        float ee = __expf(lrelu(a1s[(long)s * 8 + l] + adh));
        den += ee;
        int idx = j - beg;
        if (idx < E_CAP) {
            sh_ee[slot][idx][l] = ee;
            if (l == 0) sh_s[slot][idx] = s;
        }
    }
    #pragma unroll
    for (int off = 8; off <= 32; off <<= 1) den += __shfl_xor(den, off, 64);
    // every lane now holds den for its head l (same-wave LDS: no barrier needed)

    // ---- phase 2: weighted aggregation of h1 rows
    float acc[8] = {0.f,0.f,0.f,0.f,0.f,0.f,0.f,0.f};
    int j = beg + g;
    bool v = (j < end);
    int idx = j - beg;
    int s = v ? ((idx < E_CAP) ? sh_s[slot][idx] : ecol[j]) : 0;
    uint4 pv = *(const uint4*)(h1p + (long)s * 64 + l * 8);

    for (int j0 = beg; j0 < end; j0 += 8) {
        int jn = j + 8;
        bool vn = (jn < end);
        int idxn = jn - beg;
        int sn = vn ? ((idxn < E_CAP) ? sh_s[slot][idxn] : ecol[jn]) : 0;
        uint4 pvn = *(const uint4*)(h1p + (long)sn * 64 + l * 8);
        float w = 0.f;
        if (v) w = (idx < E_CAP) ? sh_ee[slot][idx][l]
                                 : __expf(lrelu(a1s[(long)s * 8 + l] + adh));
        acc[0] += w * bflo(pv.x); acc[1] += w * bfhi(pv.x);
        acc[2] += w * bflo(pv.y); acc[3] += w * bfhi(pv.y);
        acc[4] += w * bflo(pv.z); acc[5] += w * bfhi(pv.z);
        acc[6] += w * bflo(pv.w); acc[7] += w * bfhi(pv.w);
        j = jn; v = vn; idx = idxn; s = sn; pv = pvn;
    }
    #pragma unroll
    for (int off = 8; off <= 32; off <<= 1) {
        #pragma unroll
        for (int k = 0; k < 8; ++k) acc[k] += __shfl_xor(acc[k], off, 64);
    }

    // ---- epilogue: lanes g==0 (lane==l<8) hold head l, channels 8l..8l+7
    if (g == 0) {
        const float inv = 1.f / den;
        float pg = 0.f, ps = 0.f, pd = 0.f;
        #pragma unroll
        for (int k = 0; k < 8; ++k) {
            float vv = acc[k] * inv + bias1[l * 8 + k];
            vv = vv > 0.f ? vv : (__expf(vv) - 1.f);      // elu -> x2 channel
            pg += vv * wv[l * 8 + k];
            ps += vv * wv[64 + l * 8 + k];
            pd += vv * wv[128 + l * 8 + k];
        }
        #pragma unroll
        for (int off = 1; off < 8; off <<= 1) {
            pg += __shfl_xor(pg, off, 64);
            ps += __shfl_xor(ps, off, 64);
            pd += __shfl_xor(pd, off, 64);
        }
        if (l == 0) { sg2[dst] = make_float2(ps, pg); a2dv[dst] = pd; }
    }
}

// ---- conv2 + pool + linear, collapsed to scalars -------------------------
// out[batch[dst]] += (sum_j ee_j * g2[src_j]) / den + b2.Wg
__global__ __launch_bounds__(256) void k_gat2(
    const int* __restrict__ rowptr, const int* __restrict__ ecol,
    const float2* __restrict__ sg2, const float* __restrict__ a2dv,
    const float* __restrict__ bias2, const float* __restrict__ Wg,
    const int* __restrict__ batch, float* __restrict__ out)
{
    const int dst  = blockIdx.x * 4 + (threadIdx.x >> 6);  // grid = N/4
    const int lane = threadIdx.x & 63;
    const int beg = rowptr[dst], end = rowptr[dst + 1];
    const float adv = a2dv[dst];

    float den = 0.f, num = 0.f;
    for (int j = beg + lane; j < end; j += 64) {
        int s = ecol[j];
        float2 sg = sg2[s];                    // {a2s, g2} : 8 B, L2-resident
        float ee = __expf(lrelu(sg.x + adv));
        den += ee;
        num += ee * sg.y;
    }
    float bc = bias2[lane] * Wg[lane] + bias2[lane + 64] * Wg[lane + 64];
    #pragma unroll
    for (int off = 1; off < 64; off <<= 1) {
        den += __shfl_xor(den, off, 64);
        num += __shfl_xor(num, off, 64);
        bc  += __shfl_xor(bc,  off, 64);
    }
    if (lane == 0) atomAddF(out + batch[dst], num / den + bc);
}

extern "C" void kernel_launch(void* const* d_in, const int* in_sizes, int n_in,
                              void* d_out, int out_size, void* d_ws, size_t ws_size,
                              hipStream_t stream) {
    (void)in_sizes; (void)n_in; (void)out_size; (void)ws_size;
    const float* x     = (const float*)d_in[0];
    const int*   ei    = (const int*)d_in[1];
    const int*   batch = (const int*)d_in[2];
    const float* W1    = (const float*)d_in[3];
    const float* as1   = (const float*)d_in[4];
    const float* ad1   = (const float*)d_in[5];
    const float* b1    = (const float*)d_in[6];
    const float* W2    = (const float*)d_in[7];
    const float* as2   = (const float*)d_in[8];
    const float* ad2   = (const float*)d_in[9];
    const float* b2    = (const float*)d_in[10];
    const float* Wg    = (const float*)d_in[11];
    const float* bg    = (const float*)d_in[12];
    float* out = (float*)d_out;

    // ---- workspace layout (16-B aligned chunks; total ~30 MB) ----
    const long N = N_NODES;
    char* p = (char*)d_ws;
    int* deg    = (int*)p;              p += (N)      * sizeof(int);
    int* excl   = (int*)p;              p += (N)      * sizeof(int);
    int* rowptr = (int*)p;              p += (N + 4)  * sizeof(int);   // +4: 16B align
    int* cursor = (int*)p;              p += (N)      * sizeof(int);
    int* bsum   = (int*)p;              p += 128      * sizeof(int);
    int* ecol   = (int*)p;              p += (long)ET * sizeof(int);
    unsigned short* h1p = (unsigned short*)p; p += N * 64 * sizeof(unsigned short);
    float* a1s  = (float*)p;            p += N * 8    * sizeof(float);
    float* a1d  = (float*)p;            p += N * 8    * sizeof(float);
    float2* sg2 = (float2*)p;           p += N        * sizeof(float2);
    float* a2dv = (float*)p;            p += N        * sizeof(float);
    float* wv   = (float*)p;            p += 192      * sizeof(float);

    // ---- CSR build ----
    hipMemsetAsync(deg, 0, N * sizeof(int), stream);
    k_deg  <<<(ET + 255) / 256, 256, 0, stream>>>(ei, deg);
    k_scan1<<<NB_SCAN, SCAN_BS, 0, stream>>>(deg, excl, bsum);
    k_scan2<<<1, 128, 0, stream>>>(bsum);
    k_scan3<<<(N_NODES + 255) / 256, 256, 0, stream>>>(excl, bsum, rowptr, cursor);
    k_fill <<<(ET + 255) / 256, 256, 0, stream>>>(ei, cursor, ecol);

    // ---- conv1 (+ fused projection to conv2 scalars) ----
    k_wv   <<<1, 256, 0, stream>>>(W2, as2, ad2, Wg, wv);
    k_feat1<<<N_NODES / 4, 256, 0, stream>>>(x, W1, as1, ad1, h1p, a1s, a1d);
    k_gat1 <<<N_NODES / 4, 256, 0, stream>>>(rowptr, ecol, a1s, a1d, h1p, b1, wv, sg2, a2dv);

    // ---- conv2 + pool + linear (scalar form) ----
    k_out_init<<<2, 256, 0, stream>>>(out, bg);
    k_gat2 <<<N_NODES / 4, 256, 0, stream>>>(rowptr, ecol, sg2, a2dv, b2, Wg, batch, out);
}

// Round 7
// 512.133 us; speedup vs baseline: 1.6318x; 1.2168x over previous
//
#include <hip/hip_runtime.h>
#include <hip/hip_bf16.h>
#include <math.h>

#define N_NODES 100000
#define N_EDGES 1600000
#define ET (N_EDGES + N_NODES)   // edges + self-loops
#define N_GRAPHS 512
#define NEG_SLOPE 0.2f
#define SCAN_BS 1024
#define NB_SCAN ((N_NODES + SCAN_BS - 1) / SCAN_BS)   // 98
#define E_CAP 64        // per-dst LDS edge cap in k_gat1; overflow recomputed inline
#define G1_BLOCKS 2048  // persistent k_gat1 grid
#define G2_BLOCKS 1280  // persistent k_gat2 grid (5120 waves, 20480 subgroups)

__device__ __forceinline__ void atomAddF(float* p, float v) { unsafeAtomicAdd(p, v); }
__device__ __forceinline__ float lrelu(float v) { return v >= 0.f ? v : NEG_SLOPE * v; }

// bf16 helpers (RNE round)
__device__ __forceinline__ unsigned short f2bf(float f) {
    unsigned int u = __float_as_uint(f);
    u += 0x7FFFu + ((u >> 16) & 1u);
    return (unsigned short)(u >> 16);
}
__device__ __forceinline__ float bflo(unsigned int p) { return __uint_as_float(p << 16); }
__device__ __forceinline__ float bfhi(unsigned int p) { return __uint_as_float(p & 0xFFFF0000u); }

// ---- init ----------------------------------------------------------------
__global__ void k_out_init(float* __restrict__ out, const float* __restrict__ bg) {
    int i = blockIdx.x * blockDim.x + threadIdx.x;
    if (i < N_GRAPHS) out[i] = bg[0];
}

// ---- CSR build -----------------------------------------------------------
__global__ __launch_bounds__(256) void k_deg(const int* __restrict__ ei, int* __restrict__ deg) {
    int e = blockIdx.x * 256 + threadIdx.x;
    if (e >= ET) return;
    int dst = (e < N_EDGES) ? ei[N_EDGES + e] : (e - N_EDGES);
    atomicAdd(deg + dst, 1);
}

__global__ __launch_bounds__(SCAN_BS) void k_scan1(const int* __restrict__ deg,
                                                   int* __restrict__ excl, int* __restrict__ bsum) {
    __shared__ int sh[SCAN_BS];
    const int t = threadIdx.x;
    const int i = blockIdx.x * SCAN_BS + t;
    int v = (i < N_NODES) ? deg[i] : 0;
    sh[t] = v;
    __syncthreads();
    for (int off = 1; off < SCAN_BS; off <<= 1) {
        int a = (t >= off) ? sh[t - off] : 0;
        __syncthreads();
        sh[t] += a;
        __syncthreads();
    }
    if (i < N_NODES) excl[i] = sh[t] - v;
    if (t == SCAN_BS - 1) bsum[blockIdx.x] = sh[t];
}

__global__ __launch_bounds__(128) void k_scan2(int* __restrict__ bsum) {
    __shared__ int sh[128];
    const int t = threadIdx.x;
    int v = (t < NB_SCAN) ? bsum[t] : 0;
    sh[t] = v;
    __syncthreads();
    for (int off = 1; off < 128; off <<= 1) {
        int a = (t >= off) ? sh[t - off] : 0;
        __syncthreads();
        sh[t] += a;
        __syncthreads();
    }
    if (t < NB_SCAN) bsum[t] = sh[t] - v;   // exclusive
}

__global__ __launch_bounds__(256) void k_scan3(const int* __restrict__ excl, const int* __restrict__ bsum,
                                               int* __restrict__ rowptr, int* __restrict__ cursor) {
    int i = blockIdx.x * 256 + threadIdx.x;
    if (i < N_NODES) {
        int r = excl[i] + bsum[i / SCAN_BS];
        rowptr[i] = r;
        cursor[i] = r;
    }
    if (i == 0) rowptr[N_NODES] = ET;
}

__global__ __launch_bounds__(256) void k_fill(const int* __restrict__ ei,
                                              int* __restrict__ cursor, int* __restrict__ ecol) {
    int e = blockIdx.x * 256 + threadIdx.x;
    if (e >= ET) return;
    int src, dst;
    if (e < N_EDGES) { src = ei[e]; dst = ei[N_EDGES + e]; }
    else             { src = dst = e - N_EDGES; }
    int slot = atomicAdd(cursor + dst, 1);
    ecol[slot] = src;
}

// ---- precompute wv = {W2@Wg, W2@as2^T, W2@ad2^T} (3x64) + wv[192]=b2.Wg --
__global__ __launch_bounds__(256) void k_wv(
    const float* __restrict__ W2, const float* __restrict__ as2,
    const float* __restrict__ ad2, const float* __restrict__ Wg,
    const float* __restrict__ b2, float* __restrict__ wv)
{
    int i = threadIdx.x;
    if (i < 192) {
        int c = i & 63, which = i >> 6;
        const float* v = (which == 0) ? Wg : ((which == 1) ? as2 : ad2);
        float s = 0.f;
        #pragma unroll
        for (int t = 0; t < 128; ++t) s += W2[c * 128 + t] * v[t];
        wv[which * 64 + c] = s;
    } else if (i == 192) {
        float s = 0.f;
        #pragma unroll
        for (int t = 0; t < 128; ++t) s += b2[t] * Wg[t];
        wv[192] = s;
    }
}

// ---- conv1 features: h1p = bf16(x@W1) [N,64]; a1s/a1d fp32 [N,8] ---------
__global__ __launch_bounds__(256) void k_feat1(
    const float* __restrict__ x, const float* __restrict__ W1,
    const float* __restrict__ as1, const float* __restrict__ ad1,
    unsigned short* __restrict__ h1p, float* __restrict__ a1s, float* __restrict__ a1d)
{
    __shared__ float xs[4][76];
    const int g = threadIdx.x >> 6;
    const int c = threadIdx.x & 63;
    const int n = blockIdx.x * 4 + g;  // grid = N/4 exactly
    const float* xr = x + (long)n * 75;
    xs[g][c] = xr[c];
    if (c < 11) xs[g][64 + c] = xr[64 + c];
    __syncthreads();
    float h = 0.f;
    #pragma unroll
    for (int k = 0; k < 75; ++k) h += xs[g][k] * W1[k * 64 + c];
    h1p[(long)n * 64 + c] = f2bf(h);
    const int head = c >> 3, lane = c & 7;
    float vs = h * as1[c];
    float vd = h * ad1[c];
    #pragma unroll
    for (int off = 1; off < 8; off <<= 1) {
        vs += __shfl_xor(vs, off, 64);
        vd += __shfl_xor(vd, off, 64);
    }
    if (lane == 0) { a1s[n * 8 + head] = vs; a1d[n * 8 + head] = vd; }
}

// ---- conv1 gather (persistent, grid-stride): fused softmax+agg+elu+proj --
__global__ __launch_bounds__(256) void k_gat1(
    const int* __restrict__ rowptr, const int* __restrict__ ecol,
    const float* __restrict__ a1s, const float* __restrict__ a1d,
    const unsigned short* __restrict__ h1p, const float* __restrict__ bias1,
    const float* __restrict__ wv,
    float2* __restrict__ sg2, float* __restrict__ a2dv)
{
    __shared__ float sh_ee[4][E_CAP][8];   // [slot][edge][head]
    __shared__ int   sh_s[4][E_CAP];
    const int slot = threadIdx.x >> 6;
    const int lane = threadIdx.x & 63;
    const int g = lane >> 3;     // edge-group
    const int l = lane & 7;      // head / channel-block
    const int stride = gridDim.x * 4;

    for (int base = blockIdx.x * 4; base < N_NODES; base += stride) {
        const int dst = base + slot;              // N%4==0 -> always valid
        const int beg = rowptr[dst], end = rowptr[dst + 1];
        const float adh = a1d[(long)dst * 8 + l];

        // phase 1: attention weights -> LDS (and den over ALL edges)
        float den = 0.f;
        for (int j = beg + g; j < end; j += 8) {
            int s = ecol[j];
            float ee = __expf(lrelu(a1s[(long)s * 8 + l] + adh));
            den += ee;
            int idx = j - beg;
            if (idx < E_CAP) {
                sh_ee[slot][idx][l] = ee;
                if (l == 0) sh_s[slot][idx] = s;
            }
        }
        #pragma unroll
        for (int off = 8; off <= 32; off <<= 1) den += __shfl_xor(den, off, 64);

        // phase 2: weighted aggregation of h1 rows (pipelined)
        float acc[8] = {0.f,0.f,0.f,0.f,0.f,0.f,0.f,0.f};
        int j = beg + g;
        bool v = (j < end);
        int idx = j - beg;
        int s = v ? ((idx < E_CAP) ? sh_s[slot][idx] : ecol[j]) : 0;
        uint4 pv = *(const uint4*)(h1p + (long)s * 64 + l * 8);

        for (int j0 = beg; j0 < end; j0 += 8) {
            int jn = j + 8;
            bool vn = (jn < end);
            int idxn = jn - beg;
            int sn = vn ? ((idxn < E_CAP) ? sh_s[slot][idxn] : ecol[jn]) : 0;
            uint4 pvn = *(const uint4*)(h1p + (long)sn * 64 + l * 8);
            float w = 0.f;
            if (v) w = (idx < E_CAP) ? sh_ee[slot][idx][l]
                                     : __expf(lrelu(a1s[(long)s * 8 + l] + adh));
            acc[0] += w * bflo(pv.x); acc[1] += w * bfhi(pv.x);
            acc[2] += w * bflo(pv.y); acc[3] += w * bfhi(pv.y);
            acc[4] += w * bflo(pv.z); acc[5] += w * bfhi(pv.z);
            acc[6] += w * bflo(pv.w); acc[7] += w * bfhi(pv.w);
            j = jn; v = vn; idx = idxn; s = sn; pv = pvn;
        }
        #pragma unroll
        for (int off = 8; off <= 32; off <<= 1) {
            #pragma unroll
            for (int k = 0; k < 8; ++k) acc[k] += __shfl_xor(acc[k], off, 64);
        }

        // epilogue: lanes g==0 hold head l, channels 8l..8l+7
        if (g == 0) {
            const float inv = 1.f / den;
            float pg = 0.f, ps = 0.f, pd = 0.f;
            #pragma unroll
            for (int k = 0; k < 8; ++k) {
                float vv = acc[k] * inv + bias1[l * 8 + k];
                vv = vv > 0.f ? vv : (__expf(vv) - 1.f);      // elu -> x2 channel
                pg += vv * wv[l * 8 + k];
                ps += vv * wv[64 + l * 8 + k];
                pd += vv * wv[128 + l * 8 + k];
            }
            #pragma unroll
            for (int off = 1; off < 8; off <<= 1) {
                pg += __shfl_xor(pg, off, 64);
                ps += __shfl_xor(ps, off, 64);
                pd += __shfl_xor(pd, off, 64);
            }
            if (l == 0) { sg2[dst] = make_float2(ps, pg); a2dv[dst] = pd; }
        }
    }
}

// ---- conv2 + pool + linear (persistent, 16-lane subgroups) ---------------
// Each subgroup owns a contiguous node strip; per-graph partial kept in a
// register and flushed on graph change (batch is sorted).
__global__ __launch_bounds__(256) void k_gat2(
    const int* __restrict__ rowptr, const int* __restrict__ ecol,
    const float2* __restrict__ sg2, const float* __restrict__ a2dv,
    const float* __restrict__ wv, const int* __restrict__ batch,
    float* __restrict__ out)
{
    const int lane = threadIdx.x & 63;
    const int sl = lane & 15;                          // lane within subgroup
    const int sgid = ((blockIdx.x * 256 + threadIdx.x) >> 4);  // global subgroup
    const int NS = G2_BLOCKS * 16;                     // total subgroups
    const int per = (N_NODES + NS - 1) / NS;           // nodes per subgroup
    const int n0 = sgid * per;
    const int n1 = min(n0 + per, N_NODES);
    const float bc = wv[192];                          // b2 . Wg

    float accg = 0.f;
    int curg = -1;
    for (int n = n0; n < n1; ++n) {
        const int beg = rowptr[n], end = rowptr[n + 1];
        const float adv = a2dv[n];
        float num = 0.f, den = 0.f;
        for (int j = beg + sl; j < end; j += 16) {
            int s = ecol[j];
            float2 v = sg2[s];                 // {a2s, g2}: 8 B, L2-resident
            float ee = __expf(lrelu(v.x + adv));
            den += ee;
            num += ee * v.y;
        }
        #pragma unroll
        for (int off = 1; off < 16; off <<= 1) {   // stays within 16-lane group
            den += __shfl_xor(den, off, 64);
            num += __shfl_xor(num, off, 64);
        }
        if (sl == 0) {
            int gr = batch[n];
            if (gr != curg) {
                if (curg >= 0) atomAddF(out + curg, accg);
                curg = gr; accg = 0.f;
            }
            accg += num / den + bc;
        }
    }
    if (sl == 0 && curg >= 0) atomAddF(out + curg, accg);
}

extern "C" void kernel_launch(void* const* d_in, const int* in_sizes, int n_in,
                              void* d_out, int out_size, void* d_ws, size_t ws_size,
                              hipStream_t stream) {
    (void)in_sizes; (void)n_in; (void)out_size; (void)ws_size;
    const float* x     = (const float*)d_in[0];
    const int*   ei    = (const int*)d_in[1];
    const int*   batch = (const int*)d_in[2];
    const float* W1    = (const float*)d_in[3];
    const float* as1   = (const float*)d_in[4];
    const float* ad1   = (const float*)d_in[5];
    const float* b1    = (const float*)d_in[6];
    const float* W2    = (const float*)d_in[7];
    const float* as2   = (const float*)d_in[8];
    const float* ad2   = (const float*)d_in[9];
    const float* b2    = (const float*)d_in[10];
    const float* Wg    = (const float*)d_in[11];
    const float* bg    = (const float*)d_in[12];
    float* out = (float*)d_out;

    // ---- workspace layout (16-B aligned chunks; total ~30 MB) ----
    const long N = N_NODES;
    char* p = (char*)d_ws;
    int* deg    = (int*)p;              p += (N)      * sizeof(int);
    int* excl   = (int*)p;              p += (N)      * sizeof(int);
    int* rowptr = (int*)p;              p += (N + 4)  * sizeof(int);   // +4: 16B align
    int* cursor = (int*)p;              p += (N)      * sizeof(int);
    int* bsum   = (int*)p;              p += 128      * sizeof(int);
    int* ecol   = (int*)p;              p += (long)ET * sizeof(int);
    unsigned short* h1p = (unsigned short*)p; p += N * 64 * sizeof(unsigned short);
    float* a1s  = (float*)p;            p += N * 8    * sizeof(float);
    float* a1d  = (float*)p;            p += N * 8    * sizeof(float);
    float2* sg2 = (float2*)p;           p += N        * sizeof(float2);
    float* a2dv = (float*)p;            p += N        * sizeof(float);
    float* wv   = (float*)p;            p += 256      * sizeof(float);

    // ---- CSR build ----
    hipMemsetAsync(deg, 0, N * sizeof(int), stream);
    k_deg  <<<(ET + 255) / 256, 256, 0, stream>>>(ei, deg);
    k_scan1<<<NB_SCAN, SCAN_BS, 0, stream>>>(deg, excl, bsum);
    k_scan2<<<1, 128, 0, stream>>>(bsum);
    k_scan3<<<(N_NODES + 255) / 256, 256, 0, stream>>>(excl, bsum, rowptr, cursor);
    k_fill <<<(ET + 255) / 256, 256, 0, stream>>>(ei, cursor, ecol);

    // ---- conv1 (+ fused projection to conv2 scalars) ----
    k_wv   <<<1, 256, 0, stream>>>(W2, as2, ad2, Wg, b2, wv);
    k_feat1<<<N_NODES / 4, 256, 0, stream>>>(x, W1, as1, ad1, h1p, a1s, a1d);
    k_gat1 <<<G1_BLOCKS, 256, 0, stream>>>(rowptr, ecol, a1s, a1d, h1p, b1, wv, sg2, a2dv);

    // ---- conv2 + pool + linear (scalar form, persistent) ----
    k_out_init<<<2, 256, 0, stream>>>(out, bg);
    k_gat2 <<<G2_BLOCKS, 256, 0, stream>>>(rowptr, ecol, sg2, a2dv, wv, batch, out);
}

// Round 8
// 368.373 us; speedup vs baseline: 2.2686x; 1.3903x over previous
//
#include <hip/hip_runtime.h>
#include <hip/hip_bf16.h>
#include <math.h>

#define N_NODES 100000
#define N_EDGES 1600000
#define ET (N_EDGES + N_NODES)   // edges + self-loops
#define N_GRAPHS 512
#define NEG_SLOPE 0.2f
#define E_CAP 64        // per-dst LDS edge cap in k_gat1; overflow recomputed inline
#define G1_BLOCKS 2048  // persistent k_gat1 grid
#define G2_BLOCKS 1280  // persistent k_gat2 grid

// ---- bucketed CSR build params ----
#define BSH 9                       // 512 nodes per bucket
#define NBUCK ((N_NODES + 511) / 512)         // 196
#define BCAP 10240                  // per-bucket region capacity (mean 8704, 17 sigma slack)
#define CHUNK ((ET + 255) / 256)    // 6641 edges per k_binA block

__device__ __forceinline__ void atomAddF(float* p, float v) { unsafeAtomicAdd(p, v); }
__device__ __forceinline__ float lrelu(float v) { return v >= 0.f ? v : NEG_SLOPE * v; }

// bf16 helpers (RNE round)
__device__ __forceinline__ unsigned short f2bf(float f) {
    unsigned int u = __float_as_uint(f);
    u += 0x7FFFu + ((u >> 16) & 1u);
    return (unsigned short)(u >> 16);
}
__device__ __forceinline__ float bflo(unsigned int p) { return __uint_as_float(p << 16); }
__device__ __forceinline__ float bfhi(unsigned int p) { return __uint_as_float(p & 0xFFFF0000u); }

// ---- init ----------------------------------------------------------------
__global__ void k_out_init(float* __restrict__ out, const float* __restrict__ bg) {
    int i = blockIdx.x * blockDim.x + threadIdx.x;
    if (i < N_GRAPHS) out[i] = bg[0];
}

// ---- CSR build, pass A: per-chunk LDS counting sort by bucket ------------
__global__ __launch_bounds__(256) void k_binA(
    const int* __restrict__ ei, uint2* __restrict__ gbuf, int* __restrict__ bcur)
{
    __shared__ uint2 pairs[CHUNK];
    __shared__ int hist[NBUCK], excl[NBUCK], gbase[NBUCK], cnt2[NBUCK];
    const int t = threadIdx.x;
    const long e0 = (long)blockIdx.x * CHUNK;
    const int  n  = (int)((e0 + CHUNK <= ET) ? CHUNK : (ET - e0));
    for (int i = t; i < NBUCK; i += 256) { hist[i] = 0; cnt2[i] = 0; }
    __syncthreads();
    // local histogram by bucket
    for (int i = t; i < n; i += 256) {
        long e = e0 + i;
        int dst = (e < N_EDGES) ? ei[N_EDGES + e] : (int)(e - N_EDGES);
        atomicAdd(&hist[dst >> BSH], 1);
    }
    __syncthreads();
    if (t == 0) {            // serial scan of 196 - cheap
        int acc = 0;
        for (int b = 0; b < NBUCK; ++b) { excl[b] = acc; acc += hist[b]; }
    }
    __syncthreads();
    // scatter chunk edges into LDS, bucket-sorted
    for (int i = t; i < n; i += 256) {
        long e = e0 + i;
        int src, dst;
        if (e < N_EDGES) { src = ei[e]; dst = ei[N_EDGES + e]; }
        else             { src = dst = (int)(e - N_EDGES); }
        int b = dst >> BSH;
        int pos = excl[b] + atomicAdd(&cnt2[b], 1);
        pairs[pos] = make_uint2((unsigned)src, (unsigned)dst);
    }
    __syncthreads();
    // reserve global space: ONE atomic per (block,bucket)
    for (int b = t; b < NBUCK; b += 256)
        gbase[b] = hist[b] ? atomicAdd(&bcur[b], hist[b]) : 0;
    __syncthreads();
    // flush contiguous runs to bucket regions (coalesced 8-B stores)
    for (int i = t; i < n; i += 256) {
        uint2 pr = pairs[i];
        int b = (int)(pr.y >> BSH);
        gbuf[(long)b * BCAP + gbase[b] + (i - excl[b])] = pr;
    }
}

// ---- CSR build: scan of bucket counts ------------------------------------
__global__ void k_bscan(const int* __restrict__ bcur, int* __restrict__ cbase) {
    if (threadIdx.x == 0) {
        int acc = 0;
        for (int b = 0; b < NBUCK; ++b) { cbase[b] = acc; acc += bcur[b]; }
        cbase[NBUCK] = acc;   // == ET
    }
}

// ---- CSR build, pass B: per-bucket fine CSR (LDS histogram + scan) -------
__global__ __launch_bounds__(256) void k_binB(
    const uint2* __restrict__ gbuf, const int* __restrict__ bcur,
    const int* __restrict__ cbase, int* __restrict__ rowptr, int* __restrict__ ecol)
{
    __shared__ int hist[512], excl[512], cnt2[512];
    const int b = blockIdx.x;
    const int t = threadIdx.x;
    const int cnt  = bcur[b];
    const int base = cbase[b];
    const int d0 = b << BSH;
    const int nloc = (N_NODES - d0 < 512) ? (N_NODES - d0) : 512;
    for (int i = t; i < nloc; i += 256) { hist[i] = 0; cnt2[i] = 0; }
    __syncthreads();
    const uint2* eb = gbuf + (long)b * BCAP;
    for (int i = t; i < cnt; i += 256) atomicAdd(&hist[(int)eb[i].y - d0], 1);
    __syncthreads();
    if (t == 0) {            // serial scan of <=512 - parallel across 196 blocks
        int acc = 0;
        for (int k = 0; k < nloc; ++k) { excl[k] = acc; acc += hist[k]; }
    }
    __syncthreads();
    for (int k = t; k < nloc; k += 256) rowptr[d0 + k] = base + excl[k];
    if (b == NBUCK - 1 && t == 0) rowptr[N_NODES] = base + cnt;   // == ET
    for (int i = t; i < cnt; i += 256) {
        uint2 pr = eb[i];
        int dl = (int)pr.y - d0;
        int slot = excl[dl] + atomicAdd(&cnt2[dl], 1);
        ecol[base + slot] = (int)pr.x;
    }
}

// ---- precompute wv = {W2@Wg, W2@as2^T, W2@ad2^T} (3x64) + wv[192]=b2.Wg --
__global__ __launch_bounds__(256) void k_wv(
    const float* __restrict__ W2, const float* __restrict__ as2,
    const float* __restrict__ ad2, const float* __restrict__ Wg,
    const float* __restrict__ b2, float* __restrict__ wv)
{
    int i = threadIdx.x;
    if (i < 192) {
        int c = i & 63, which = i >> 6;
        const float* v = (which == 0) ? Wg : ((which == 1) ? as2 : ad2);
        float s = 0.f;
        #pragma unroll
        for (int t = 0; t < 128; ++t) s += W2[c * 128 + t] * v[t];
        wv[which * 64 + c] = s;
    } else if (i == 192) {
        float s = 0.f;
        #pragma unroll
        for (int t = 0; t < 128; ++t) s += b2[t] * Wg[t];
        wv[192] = s;
    }
}

// ---- conv1 features: h1p = bf16(x@W1) [N,64]; a1s/a1d fp32 [N,8] ---------
__global__ __launch_bounds__(256) void k_feat1(
    const float* __restrict__ x, const float* __restrict__ W1,
    const float* __restrict__ as1, const float* __restrict__ ad1,
    unsigned short* __restrict__ h1p, float* __restrict__ a1s, float* __restrict__ a1d)
{
    __shared__ float xs[4][76];
    const int g = threadIdx.x >> 6;
    const int c = threadIdx.x & 63;
    const int n = blockIdx.x * 4 + g;  // grid = N/4 exactly
    const float* xr = x + (long)n * 75;
    xs[g][c] = xr[c];
    if (c < 11) xs[g][64 + c] = xr[64 + c];
    __syncthreads();
    float h = 0.f;
    #pragma unroll
    for (int k = 0; k < 75; ++k) h += xs[g][k] * W1[k * 64 + c];
    h1p[(long)n * 64 + c] = f2bf(h);
    const int head = c >> 3, lane = c & 7;
    float vs = h * as1[c];
    float vd = h * ad1[c];
    #pragma unroll
    for (int off = 1; off < 8; off <<= 1) {
        vs += __shfl_xor(vs, off, 64);
        vd += __shfl_xor(vd, off, 64);
    }
    if (lane == 0) { a1s[n * 8 + head] = vs; a1d[n * 8 + head] = vd; }
}

// ---- conv1 gather (persistent, grid-stride): fused softmax+agg+elu+proj --
__global__ __launch_bounds__(256) void k_gat1(
    const int* __restrict__ rowptr, const int* __restrict__ ecol,
    const float* __restrict__ a1s, const float* __restrict__ a1d,
    const unsigned short* __restrict__ h1p, const float* __restrict__ bias1,
    const float* __restrict__ wv,
    float2* __restrict__ sg2, float* __restrict__ a2dv)
{
    __shared__ float sh_ee[4][E_CAP][8];   // [slot][edge][head]
    __shared__ int   sh_s[4][E_CAP];
    const int slot = threadIdx.x >> 6;
    const int lane = threadIdx.x & 63;
    const int g = lane >> 3;     // edge-group
    const int l = lane & 7;      // head / channel-block
    const int stride = gridDim.x * 4;

    for (int base = blockIdx.x * 4; base < N_NODES; base += stride) {
        const int dst = base + slot;              // N%4==0 -> always valid
        const int beg = rowptr[dst], end = rowptr[dst + 1];
        const float adh = a1d[(long)dst * 8 + l];

        // phase 1: attention weights -> LDS (and den over ALL edges)
        float den = 0.f;
        for (int j = beg + g; j < end; j += 8) {
            int s = ecol[j];
            float ee = __expf(lrelu(a1s[(long)s * 8 + l] + adh));
            den += ee;
            int idx = j - beg;
            if (idx < E_CAP) {
                sh_ee[slot][idx][l] = ee;
                if (l == 0) sh_s[slot][idx] = s;
            }
        }
        #pragma unroll
        for (int off = 8; off <= 32; off <<= 1) den += __shfl_xor(den, off, 64);

        // phase 2: weighted aggregation of h1 rows (pipelined)
        float acc[8] = {0.f,0.f,0.f,0.f,0.f,0.f,0.f,0.f};
        int j = beg + g;
        bool v = (j < end);
        int idx = j - beg;
        int s = v ? ((idx < E_CAP) ? sh_s[slot][idx] : ecol[j]) : 0;
        uint4 pv = *(const uint4*)(h1p + (long)s * 64 + l * 8);

        for (int j0 = beg; j0 < end; j0 += 8) {
            int jn = j + 8;
            bool vn = (jn < end);
            int idxn = jn - beg;
            int sn = vn ? ((idxn < E_CAP) ? sh_s[slot][idxn] : ecol[jn]) : 0;
            uint4 pvn = *(const uint4*)(h1p + (long)sn * 64 + l * 8);
            float w = 0.f;
            if (v) w = (idx < E_CAP) ? sh_ee[slot][idx][l]
                                     : __expf(lrelu(a1s[(long)s * 8 + l] + adh));
            acc[0] += w * bflo(pv.x); acc[1] += w * bfhi(pv.x);
            acc[2] += w * bflo(pv.y); acc[3] += w * bfhi(pv.y);
            acc[4] += w * bflo(pv.z); acc[5] += w * bfhi(pv.z);
            acc[6] += w * bflo(pv.w); acc[7] += w * bfhi(pv.w);
            j = jn; v = vn; idx = idxn; s = sn; pv = pvn;
        }
        #pragma unroll
        for (int off = 8; off <= 32; off <<= 1) {
            #pragma unroll
            for (int k = 0; k < 8; ++k) acc[k] += __shfl_xor(acc[k], off, 64);
        }

        // epilogue: lanes g==0 hold head l, channels 8l..8l+7
        if (g == 0) {
            const float inv = 1.f / den;
            float pg = 0.f, ps = 0.f, pd = 0.f;
            #pragma unroll
            for (int k = 0; k < 8; ++k) {
                float vv = acc[k] * inv + bias1[l * 8 + k];
                vv = vv > 0.f ? vv : (__expf(vv) - 1.f);      // elu -> x2 channel
                pg += vv * wv[l * 8 + k];
                ps += vv * wv[64 + l * 8 + k];
                pd += vv * wv[128 + l * 8 + k];
            }
            #pragma unroll
            for (int off = 1; off < 8; off <<= 1) {
                pg += __shfl_xor(pg, off, 64);
                ps += __shfl_xor(ps, off, 64);
                pd += __shfl_xor(pd, off, 64);
            }
            if (l == 0) { sg2[dst] = make_float2(ps, pg); a2dv[dst] = pd; }
        }
    }
}

// ---- conv2 + pool + linear (persistent, 16-lane subgroups) ---------------
__global__ __launch_bounds__(256) void k_gat2(
    const int* __restrict__ rowptr, const int* __restrict__ ecol,
    const float2* __restrict__ sg2, const float* __restrict__ a2dv,
    const float* __restrict__ wv, const int* __restrict__ batch,
    float* __restrict__ out)
{
    const int lane = threadIdx.x & 63;
    const int sl = lane & 15;                          // lane within subgroup
    const int sgid = ((blockIdx.x * 256 + threadIdx.x) >> 4);  // global subgroup
    const int NS = G2_BLOCKS * 16;                     // total subgroups
    const int per = (N_NODES + NS - 1) / NS;           // nodes per subgroup
    const int n0 = sgid * per;
    const int n1 = min(n0 + per, N_NODES);
    const float bc = wv[192];                          // b2 . Wg

    float accg = 0.f;
    int curg = -1;
    for (int n = n0; n < n1; ++n) {
        const int beg = rowptr[n], end = rowptr[n + 1];
        const float adv = a2dv[n];
        float num = 0.f, den = 0.f;
        for (int j = beg + sl; j < end; j += 16) {
            int s = ecol[j];
            float2 v = sg2[s];                 // {a2s, g2}: 8 B, L2-resident
            float ee = __expf(lrelu(v.x + adv));
            den += ee;
            num += ee * v.y;
        }
        #pragma unroll
        for (int off = 1; off < 16; off <<= 1) {   // stays within 16-lane group
            den += __shfl_xor(den, off, 64);
            num += __shfl_xor(num, off, 64);
        }
        if (sl == 0) {
            int gr = batch[n];
            if (gr != curg) {
                if (curg >= 0) atomAddF(out + curg, accg);
                curg = gr; accg = 0.f;
            }
            accg += num / den + bc;
        }
    }
    if (sl == 0 && curg >= 0) atomAddF(out + curg, accg);
}

extern "C" void kernel_launch(void* const* d_in, const int* in_sizes, int n_in,
                              void* d_out, int out_size, void* d_ws, size_t ws_size,
                              hipStream_t stream) {
    (void)in_sizes; (void)n_in; (void)out_size; (void)ws_size;
    const float* x     = (const float*)d_in[0];
    const int*   ei    = (const int*)d_in[1];
    const int*   batch = (const int*)d_in[2];
    const float* W1    = (const float*)d_in[3];
    const float* as1   = (const float*)d_in[4];
    const float* ad1   = (const float*)d_in[5];
    const float* b1    = (const float*)d_in[6];
    const float* W2    = (const float*)d_in[7];
    const float* as2   = (const float*)d_in[8];
    const float* ad2   = (const float*)d_in[9];
    const float* b2    = (const float*)d_in[10];
    const float* Wg    = (const float*)d_in[11];
    const float* bg    = (const float*)d_in[12];
    float* out = (float*)d_out;

    // ---- workspace layout (16-B aligned chunks; total ~46 MB) ----
    const long N = N_NODES;
    char* p = (char*)d_ws;
    int* rowptr = (int*)p;              p += (N + 4)        * sizeof(int);
    int* bcur   = (int*)p;              p += 256            * sizeof(int);
    int* cbase  = (int*)p;              p += 256            * sizeof(int);
    int* ecol   = (int*)p;              p += (long)ET       * sizeof(int);
    uint2* gbuf = (uint2*)p;            p += (long)NBUCK * BCAP * sizeof(uint2);
    unsigned short* h1p = (unsigned short*)p; p += N * 64   * sizeof(unsigned short);
    float* a1s  = (float*)p;            p += N * 8          * sizeof(float);
    float* a1d  = (float*)p;            p += N * 8          * sizeof(float);
    float2* sg2 = (float2*)p;           p += N              * sizeof(float2);
    float* a2dv = (float*)p;            p += N              * sizeof(float);
    float* wv   = (float*)p;            p += 256            * sizeof(float);

    // ---- CSR build (bucketed two-pass) ----
    hipMemsetAsync(bcur, 0, NBUCK * sizeof(int), stream);
    k_binA <<<256, 256, 0, stream>>>(ei, gbuf, bcur);
    k_bscan<<<1, 64, 0, stream>>>(bcur, cbase);
    k_binB <<<NBUCK, 256, 0, stream>>>(gbuf, bcur, cbase, rowptr, ecol);

    // ---- conv1 (+ fused projection to conv2 scalars) ----
    k_wv   <<<1, 256, 0, stream>>>(W2, as2, ad2, Wg, b2, wv);
    k_feat1<<<N_NODES / 4, 256, 0, stream>>>(x, W1, as1, ad1, h1p, a1s, a1d);
    k_gat1 <<<G1_BLOCKS, 256, 0, stream>>>(rowptr, ecol, a1s, a1d, h1p, b1, wv, sg2, a2dv);

    // ---- conv2 + pool + linear (scalar form, persistent) ----
    k_out_init<<<2, 256, 0, stream>>>(out, bg);
    k_gat2 <<<G2_BLOCKS, 256, 0, stream>>>(rowptr, ecol, sg2, a2dv, wv, batch, out);
}

// Round 9
// 343.717 us; speedup vs baseline: 2.4314x; 1.0717x over previous
//
#include <hip/hip_runtime.h>
#include <hip/hip_bf16.h>
#include <math.h>

#define N_NODES 100000
#define N_EDGES 1600000
#define ET (N_EDGES + N_NODES)   // edges + self-loops
#define N_GRAPHS 512
#define NEG_SLOPE 0.2f
#define G1_BLOCKS 2048  // persistent k_gat1 grid
#define G2_BLOCKS 1280  // persistent k_gat2 grid

// ---- bucketed CSR build params ----
#define BSH 9                       // 512 nodes per bucket
#define NBUCK ((N_NODES + 511) / 512)         // 196
#define BCAP 10240                  // per-bucket region capacity
#define CHUNK ((ET + 255) / 256)    // 6641 edges per k_binA block

__device__ __forceinline__ void atomAddF(float* p, float v) { unsafeAtomicAdd(p, v); }
__device__ __forceinline__ float lrelu(float v) { return v >= 0.f ? v : NEG_SLOPE * v; }

// bf16 helpers (RNE round)
__device__ __forceinline__ unsigned short f2bf(float f) {
    unsigned int u = __float_as_uint(f);
    u += 0x7FFFu + ((u >> 16) & 1u);
    return (unsigned short)(u >> 16);
}
__device__ __forceinline__ float bf2f(unsigned short s) { return __uint_as_float(((unsigned int)s) << 16); }
__device__ __forceinline__ float bflo(unsigned int p) { return __uint_as_float(p << 16); }
__device__ __forceinline__ float bfhi(unsigned int p) { return __uint_as_float(p & 0xFFFF0000u); }

// ---- init ----------------------------------------------------------------
__global__ void k_out_init(float* __restrict__ out, const float* __restrict__ bg) {
    int i = blockIdx.x * blockDim.x + threadIdx.x;
    if (i < N_GRAPHS) out[i] = bg[0];
}

// ---- CSR build, pass A: per-chunk LDS counting sort by bucket ------------
__global__ __launch_bounds__(256) void k_binA(
    const int* __restrict__ ei, uint2* __restrict__ gbuf, int* __restrict__ bcur)
{
    __shared__ uint2 pairs[CHUNK];
    __shared__ int hist[NBUCK], excl[NBUCK], gbase[NBUCK], cnt2[NBUCK];
    const int t = threadIdx.x;
    const long e0 = (long)blockIdx.x * CHUNK;
    const int  n  = (int)((e0 + CHUNK <= ET) ? CHUNK : (ET - e0));
    for (int i = t; i < NBUCK; i += 256) { hist[i] = 0; cnt2[i] = 0; }
    __syncthreads();
    for (int i = t; i < n; i += 256) {
        long e = e0 + i;
        int dst = (e < N_EDGES) ? ei[N_EDGES + e] : (int)(e - N_EDGES);
        atomicAdd(&hist[dst >> BSH], 1);
    }
    __syncthreads();
    if (t == 0) {            // serial scan of 196 - cheap
        int acc = 0;
        for (int b = 0; b < NBUCK; ++b) { excl[b] = acc; acc += hist[b]; }
    }
    __syncthreads();
    for (int i = t; i < n; i += 256) {
        long e = e0 + i;
        int src, dst;
        if (e < N_EDGES) { src = ei[e]; dst = ei[N_EDGES + e]; }
        else             { src = dst = (int)(e - N_EDGES); }
        int b = dst >> BSH;
        int pos = excl[b] + atomicAdd(&cnt2[b], 1);
        pairs[pos] = make_uint2((unsigned)src, (unsigned)dst);
    }
    __syncthreads();
    for (int b = t; b < NBUCK; b += 256)
        gbase[b] = hist[b] ? atomicAdd(&bcur[b], hist[b]) : 0;
    __syncthreads();
    for (int i = t; i < n; i += 256) {
        uint2 pr = pairs[i];
        int b = (int)(pr.y >> BSH);
        gbuf[(long)b * BCAP + gbase[b] + (i - excl[b])] = pr;
    }
}

// ---- CSR build: scan of bucket counts ------------------------------------
__global__ void k_bscan(const int* __restrict__ bcur, int* __restrict__ cbase) {
    if (threadIdx.x == 0) {
        int acc = 0;
        for (int b = 0; b < NBUCK; ++b) { cbase[b] = acc; acc += bcur[b]; }
        cbase[NBUCK] = acc;   // == ET
    }
}

// ---- CSR build, pass B: per-bucket fine CSR (LDS histogram + scan) -------
__global__ __launch_bounds__(256) void k_binB(
    const uint2* __restrict__ gbuf, const int* __restrict__ bcur,
    const int* __restrict__ cbase, int* __restrict__ rowptr, int* __restrict__ ecol)
{
    __shared__ int hist[512], excl[512], cnt2[512];
    const int b = blockIdx.x;
    const int t = threadIdx.x;
    const int cnt  = bcur[b];
    const int base = cbase[b];
    const int d0 = b << BSH;
    const int nloc = (N_NODES - d0 < 512) ? (N_NODES - d0) : 512;
    for (int i = t; i < nloc; i += 256) { hist[i] = 0; cnt2[i] = 0; }
    __syncthreads();
    const uint2* eb = gbuf + (long)b * BCAP;
    for (int i = t; i < cnt; i += 256) atomicAdd(&hist[(int)eb[i].y - d0], 1);
    __syncthreads();
    if (t == 0) {
        int acc = 0;
        for (int k = 0; k < nloc; ++k) { excl[k] = acc; acc += hist[k]; }
    }
    __syncthreads();
    for (int k = t; k < nloc; k += 256) rowptr[d0 + k] = base + excl[k];
    if (b == NBUCK - 1 && t == 0) rowptr[N_NODES] = base + cnt;   // == ET
    for (int i = t; i < cnt; i += 256) {
        uint2 pr = eb[i];
        int dl = (int)pr.y - d0;
        int slot = excl[dl] + atomicAdd(&cnt2[dl], 1);
        ecol[base + slot] = (int)pr.x;
    }
}

// ---- precompute wv = {W2@Wg, W2@as2^T, W2@ad2^T} (3x64) + wv[192]=b2.Wg --
__global__ __launch_bounds__(256) void k_wv(
    const float* __restrict__ W2, const float* __restrict__ as2,
    const float* __restrict__ ad2, const float* __restrict__ Wg,
    const float* __restrict__ b2, float* __restrict__ wv)
{
    int i = threadIdx.x;
    if (i < 192) {
        int c = i & 63, which = i >> 6;
        const float* v = (which == 0) ? Wg : ((which == 1) ? as2 : ad2);
        float s = 0.f;
        #pragma unroll
        for (int t = 0; t < 128; ++t) s += W2[c * 128 + t] * v[t];
        wv[which * 64 + c] = s;
    } else if (i == 192) {
        float s = 0.f;
        #pragma unroll
        for (int t = 0; t < 128; ++t) s += b2[t] * Wg[t];
        wv[192] = s;
    }
}

// ---- conv1 features: h1p = bf16(x@W1) [N,64]; a1sh bf16 [N,8]; a1d fp32 --
__global__ __launch_bounds__(256) void k_feat1(
    const float* __restrict__ x, const float* __restrict__ W1,
    const float* __restrict__ as1, const float* __restrict__ ad1,
    unsigned short* __restrict__ h1p, unsigned short* __restrict__ a1sh,
    float* __restrict__ a1d)
{
    __shared__ float xs[4][76];
    const int g = threadIdx.x >> 6;
    const int c = threadIdx.x & 63;
    const int n = blockIdx.x * 4 + g;  // grid = N/4 exactly
    const float* xr = x + (long)n * 75;
    xs[g][c] = xr[c];
    if (c < 11) xs[g][64 + c] = xr[64 + c];
    __syncthreads();
    float h = 0.f;
    #pragma unroll
    for (int k = 0; k < 75; ++k) h += xs[g][k] * W1[k * 64 + c];
    h1p[(long)n * 64 + c] = f2bf(h);
    const int head = c >> 3, lane = c & 7;
    float vs = h * as1[c];
    float vd = h * ad1[c];
    #pragma unroll
    for (int off = 1; off < 8; off <<= 1) {
        vs += __shfl_xor(vs, off, 64);
        vd += __shfl_xor(vd, off, 64);
    }
    if (lane == 0) { a1sh[n * 8 + head] = f2bf(vs); a1d[n * 8 + head] = vd; }
}

// ---- conv1 gather (persistent, SINGLE PASS): softmax+agg+elu+proj --------
// lane = 8*g + l : group g handles edges beg+g, beg+g+8, ...; lane owns
// head l and channels 8l..8l+7. den and acc accumulate in the same loop;
// the xor(8,16,32) reduction sums across edge-groups for both.
__global__ __launch_bounds__(256) void k_gat1(
    const int* __restrict__ rowptr, const int* __restrict__ ecol,
    const unsigned short* __restrict__ a1sh, const float* __restrict__ a1d,
    const unsigned short* __restrict__ h1p, const float* __restrict__ bias1,
    const float* __restrict__ wv,
    float2* __restrict__ sg2, float* __restrict__ a2dv)
{
    const int slot = threadIdx.x >> 6;
    const int lane = threadIdx.x & 63;
    const int g = lane >> 3;     // edge-group
    const int l = lane & 7;      // head / channel-block
    const int stride = gridDim.x * 4;

    for (int base = blockIdx.x * 4; base < N_NODES; base += stride) {
        const int dst = base + slot;              // N%4==0 -> always valid
        const int beg = rowptr[dst], end = rowptr[dst + 1];
        const float adh = a1d[(long)dst * 8 + l];

        float acc[8] = {0.f,0.f,0.f,0.f,0.f,0.f,0.f,0.f};
        float den = 0.f;

        int j = beg + g;
        bool v = (j < end);
        int s = v ? ecol[j] : 0;
        unsigned short ab = a1sh[(long)s * 8 + l];
        uint4 pv = *(const uint4*)(h1p + (long)s * 64 + l * 8);

        for (int j0 = beg; j0 < end; j0 += 8) {
            int jn = j + 8;
            bool vn = (jn < end);
            int sn = vn ? ecol[jn] : 0;
            unsigned short abn = a1sh[(long)sn * 8 + l];
            uint4 pvn = *(const uint4*)(h1p + (long)sn * 64 + l * 8);
            float ee = v ? __expf(lrelu(bf2f(ab) + adh)) : 0.f;
            den += ee;
            acc[0] += ee * bflo(pv.x); acc[1] += ee * bfhi(pv.x);
            acc[2] += ee * bflo(pv.y); acc[3] += ee * bfhi(pv.y);
            acc[4] += ee * bflo(pv.z); acc[5] += ee * bfhi(pv.z);
            acc[6] += ee * bflo(pv.w); acc[7] += ee * bfhi(pv.w);
            j = jn; v = vn; s = sn; ab = abn; pv = pvn;
        }
        #pragma unroll
        for (int off = 8; off <= 32; off <<= 1) {
            den += __shfl_xor(den, off, 64);
            #pragma unroll
            for (int k = 0; k < 8; ++k) acc[k] += __shfl_xor(acc[k], off, 64);
        }

        // epilogue: lanes g==0 hold head l, channels 8l..8l+7
        if (g == 0) {
            const float inv = 1.f / den;
            float pg = 0.f, ps = 0.f, pd = 0.f;
            #pragma unroll
            for (int k = 0; k < 8; ++k) {
                float vv = acc[k] * inv + bias1[l * 8 + k];
                vv = vv > 0.f ? vv : (__expf(vv) - 1.f);      // elu -> x2 channel
                pg += vv * wv[l * 8 + k];
                ps += vv * wv[64 + l * 8 + k];
                pd += vv * wv[128 + l * 8 + k];
            }
            #pragma unroll
            for (int off = 1; off < 8; off <<= 1) {
                pg += __shfl_xor(pg, off, 64);
                ps += __shfl_xor(ps, off, 64);
                pd += __shfl_xor(pd, off, 64);
            }
            if (l == 0) { sg2[dst] = make_float2(ps, pg); a2dv[dst] = pd; }
        }
    }
}

// ---- conv2 + pool + linear (persistent, 16-lane subgroups) ---------------
__global__ __launch_bounds__(256) void k_gat2(
    const int* __restrict__ rowptr, const int* __restrict__ ecol,
    const float2* __restrict__ sg2, const float* __restrict__ a2dv,
    const float* __restrict__ wv, const int* __restrict__ batch,
    float* __restrict__ out)
{
    const int lane = threadIdx.x & 63;
    const int sl = lane & 15;                          // lane within subgroup
    const int sgid = ((blockIdx.x * 256 + threadIdx.x) >> 4);  // global subgroup
    const int NS = G2_BLOCKS * 16;                     // total subgroups
    const int per = (N_NODES + NS - 1) / NS;           // nodes per subgroup
    const int n0 = sgid * per;
    const int n1 = min(n0 + per, N_NODES);
    const float bc = wv[192];                          // b2 . Wg

    float accg = 0.f;
    int curg = -1;
    for (int n = n0; n < n1; ++n) {
        const int beg = rowptr[n], end = rowptr[n + 1];
        const float adv = a2dv[n];
        float num = 0.f, den = 0.f;
        for (int j = beg + sl; j < end; j += 16) {
            int s = ecol[j];
            float2 v = sg2[s];                 // {a2s, g2}: 8 B, L2-resident
            float ee = __expf(lrelu(v.x + adv));
            den += ee;
            num += ee * v.y;
        }
        #pragma unroll
        for (int off = 1; off < 16; off <<= 1) {   // stays within 16-lane group
            den += __shfl_xor(den, off, 64);
            num += __shfl_xor(num, off, 64);
        }
        if (sl == 0) {
            int gr = batch[n];
            if (gr != curg) {
                if (curg >= 0) atomAddF(out + curg, accg);
                curg = gr; accg = 0.f;
            }
            accg += num / den + bc;
        }
    }
    if (sl == 0 && curg >= 0) atomAddF(out + curg, accg);
}

extern "C" void kernel_launch(void* const* d_in, const int* in_sizes, int n_in,
                              void* d_out, int out_size, void* d_ws, size_t ws_size,
                              hipStream_t stream) {
    (void)in_sizes; (void)n_in; (void)out_size; (void)ws_size;
    const float* x     = (const float*)d_in[0];
    const int*   ei    = (const int*)d_in[1];
    const int*   batch = (const int*)d_in[2];
    const float* W1    = (const float*)d_in[3];
    const float* as1   = (const float*)d_in[4];
    const float* ad1   = (const float*)d_in[5];
    const float* b1    = (const float*)d_in[6];
    const float* W2    = (const float*)d_in[7];
    const float* as2   = (const float*)d_in[8];
    const float* ad2   = (const float*)d_in[9];
    const float* b2    = (const float*)d_in[10];
    const float* Wg    = (const float*)d_in[11];
    const float* bg    = (const float*)d_in[12];
    float* out = (float*)d_out;

    // ---- workspace layout (16-B aligned chunks; total ~45 MB) ----
    const long N = N_NODES;
    char* p = (char*)d_ws;
    int* rowptr = (int*)p;              p += (N + 4)        * sizeof(int);
    int* bcur   = (int*)p;              p += 256            * sizeof(int);
    int* cbase  = (int*)p;              p += 256            * sizeof(int);
    int* ecol   = (int*)p;              p += (long)ET       * sizeof(int);
    uint2* gbuf = (uint2*)p;            p += (long)NBUCK * BCAP * sizeof(uint2);
    unsigned short* h1p  = (unsigned short*)p; p += N * 64  * sizeof(unsigned short);
    unsigned short* a1sh = (unsigned short*)p; p += N * 8   * sizeof(unsigned short);
    float* a1d  = (float*)p;            p += N * 8          * sizeof(float);
    float2* sg2 = (float2*)p;           p += N              * sizeof(float2);
    float* a2dv = (float*)p;            p += N              * sizeof(float);
    float* wv   = (float*)p;            p += 256            * sizeof(float);

    // ---- CSR build (bucketed two-pass) ----
    hipMemsetAsync(bcur, 0, NBUCK * sizeof(int), stream);
    k_binA <<<256, 256, 0, stream>>>(ei, gbuf, bcur);
    k_bscan<<<1, 64, 0, stream>>>(bcur, cbase);
    k_binB <<<NBUCK, 256, 0, stream>>>(gbuf, bcur, cbase, rowptr, ecol);

    // ---- conv1 (+ fused projection to conv2 scalars) ----
    k_wv   <<<1, 256, 0, stream>>>(W2, as2, ad2, Wg, b2, wv);
    k_feat1<<<N_NODES / 4, 256, 0, stream>>>(x, W1, as1, ad1, h1p, a1sh, a1d);
    k_gat1 <<<G1_BLOCKS, 256, 0, stream>>>(rowptr, ecol, a1sh, a1d, h1p, b1, wv, sg2, a2dv);

    // ---- conv2 + pool + linear (scalar form, persistent) ----
    k_out_init<<<2, 256, 0, stream>>>(out, bg);
    k_gat2 <<<G2_BLOCKS, 256, 0, stream>>>(rowptr, ecol, sg2, a2dv, wv, batch, out);
}

// Round 10
// 324.602 us; speedup vs baseline: 2.5745x; 1.0589x over previous
//
#include <hip/hip_runtime.h>
#include <hip/hip_bf16.h>
#include <math.h>

#define N_NODES 100000
#define N_EDGES 1600000
#define ET (N_EDGES + N_NODES)   // edges + self-loops
#define N_GRAPHS 512
#define NEG_SLOPE 0.2f
#define G1_BLOCKS 2048  // persistent k_gat1 grid
#define G2_BLOCKS 1280  // persistent k_gat2 grid
#define F1_BLOCKS 2048  // persistent k_feat1 grid

// ---- bucketed CSR build params ----
#define BSH 8                                 // 256 nodes per bucket
#define NBUCK ((N_NODES + 255) / 256)         // 391
#define BCAP 5120                             // per-bucket capacity (mean 4352, 12 sigma)
#define ABLK 1024                             // k_binA grid
#define CHUNK ((ET + ABLK - 1) / ABLK)        // 1661 edges per k_binA block

__device__ __forceinline__ void atomAddF(float* p, float v) { unsafeAtomicAdd(p, v); }
__device__ __forceinline__ float lrelu(float v) { return v >= 0.f ? v : NEG_SLOPE * v; }

// bf16 helpers (RNE round)
__device__ __forceinline__ unsigned short f2bf(float f) {
    unsigned int u = __float_as_uint(f);
    u += 0x7FFFu + ((u >> 16) & 1u);
    return (unsigned short)(u >> 16);
}
__device__ __forceinline__ float bf2f(unsigned short s) { return __uint_as_float(((unsigned int)s) << 16); }
__device__ __forceinline__ float bflo(unsigned int p) { return __uint_as_float(p << 16); }
__device__ __forceinline__ float bfhi(unsigned int p) { return __uint_as_float(p & 0xFFFF0000u); }

// ---- CSR build, pass A: per-chunk LDS counting sort by bucket ------------
__global__ __launch_bounds__(256) void k_binA(
    const int* __restrict__ ei, uint2* __restrict__ gbuf, int* __restrict__ bcur)
{
    __shared__ uint2 pairs[CHUNK];
    __shared__ int hist[NBUCK], excl[NBUCK], gbase[NBUCK], cnt2[NBUCK];
    const int t = threadIdx.x;
    const long e0 = (long)blockIdx.x * CHUNK;
    const int  n  = (int)((e0 + CHUNK <= ET) ? CHUNK : (ET - e0));
    for (int i = t; i < NBUCK; i += 256) { hist[i] = 0; cnt2[i] = 0; }
    __syncthreads();
    for (int i = t; i < n; i += 256) {
        long e = e0 + i;
        int dst = (e < N_EDGES) ? ei[N_EDGES + e] : (int)(e - N_EDGES);
        atomicAdd(&hist[dst >> BSH], 1);
    }
    __syncthreads();
    if (t == 0) {            // serial scan of 391 in LDS - ~1k cycles
        int acc = 0;
        for (int b = 0; b < NBUCK; ++b) { excl[b] = acc; acc += hist[b]; }
    }
    __syncthreads();
    for (int i = t; i < n; i += 256) {
        long e = e0 + i;
        int src, dst;
        if (e < N_EDGES) { src = ei[e]; dst = ei[N_EDGES + e]; }
        else             { src = dst = (int)(e - N_EDGES); }
        int b = dst >> BSH;
        int pos = excl[b] + atomicAdd(&cnt2[b], 1);
        pairs[pos] = make_uint2((unsigned)src, (unsigned)dst);
    }
    __syncthreads();
    for (int b = t; b < NBUCK; b += 256)
        gbase[b] = hist[b] ? atomicAdd(&bcur[b], hist[b]) : 0;
    __syncthreads();
    for (int i = t; i < n; i += 256) {
        uint2 pr = pairs[i];
        int b = (int)(pr.y >> BSH);
        gbuf[(long)b * BCAP + gbase[b] + (i - excl[b])] = pr;
    }
}

// ---- CSR build, pass B: per-bucket fine CSR; bucket base computed inline -
__global__ __launch_bounds__(256) void k_binB(
    const uint2* __restrict__ gbuf, const int* __restrict__ bcur,
    int* __restrict__ rowptr, int* __restrict__ ecol)
{
    __shared__ int hist[256], excl[256], cnt2[256], red[256];
    const int b = blockIdx.x;
    const int t = threadIdx.x;
    const int cnt  = bcur[b];
    const int d0 = b << BSH;
    const int nloc = (N_NODES - d0 < 256) ? (N_NODES - d0) : 256;

    // inline exclusive prefix: base = sum of bcur[0..b)
    int partial = 0;
    for (int i = t; i < b; i += 256) partial += bcur[i];
    red[t] = partial;
    __syncthreads();
    for (int off = 128; off > 0; off >>= 1) {
        if (t < off) red[t] += red[t + off];
        __syncthreads();
    }
    const int base = red[0];

    if (t < nloc) { hist[t] = 0; cnt2[t] = 0; }
    __syncthreads();
    const uint2* eb = gbuf + (long)b * BCAP;
    for (int i = t; i < cnt; i += 256) atomicAdd(&hist[(int)eb[i].y - d0], 1);
    __syncthreads();
    if (t == 0) {
        int acc = 0;
        for (int k = 0; k < nloc; ++k) { excl[k] = acc; acc += hist[k]; }
    }
    __syncthreads();
    if (t < nloc) rowptr[d0 + t] = base + excl[t];
    if (b == NBUCK - 1 && t == 0) rowptr[N_NODES] = base + cnt;   // == ET
    for (int i = t; i < cnt; i += 256) {
        uint2 pr = eb[i];
        int dl = (int)pr.y - d0;
        int slot = excl[dl] + atomicAdd(&cnt2[dl], 1);
        ecol[base + slot] = (int)pr.x;
    }
}

// ---- precompute wv (block 0) + out init (blocks 1,2) ---------------------
__global__ __launch_bounds__(256) void k_wv(
    const float* __restrict__ W2, const float* __restrict__ as2,
    const float* __restrict__ ad2, const float* __restrict__ Wg,
    const float* __restrict__ b2, const float* __restrict__ bg,
    float* __restrict__ wv, float* __restrict__ out)
{
    const int t = threadIdx.x;
    if (blockIdx.x > 0) {
        int i = (blockIdx.x - 1) * 256 + t;
        if (i < N_GRAPHS) out[i] = bg[0];
        return;
    }
    if (t < 192) {
        int c = t & 63, which = t >> 6;
        const float* v = (which == 0) ? Wg : ((which == 1) ? as2 : ad2);
        float s = 0.f;
        #pragma unroll
        for (int k = 0; k < 128; ++k) s += W2[c * 128 + k] * v[k];
        wv[which * 64 + c] = s;
    } else if (t == 192) {
        float s = 0.f;
        #pragma unroll
        for (int k = 0; k < 128; ++k) s += b2[k] * Wg[k];
        wv[192] = s;
    }
}

// ---- conv1 features (persistent): h1p bf16 [N,64]; a1sh bf16; a1d fp32 ---
__global__ __launch_bounds__(256) void k_feat1(
    const float* __restrict__ x, const float* __restrict__ W1,
    const float* __restrict__ as1, const float* __restrict__ ad1,
    unsigned short* __restrict__ h1p, unsigned short* __restrict__ a1sh,
    float* __restrict__ a1d)
{
    __shared__ float xs[4][76];
    const int g = threadIdx.x >> 6;
    const int c = threadIdx.x & 63;
    for (int nb = blockIdx.x; nb < N_NODES / 4; nb += gridDim.x) {
        const int n = nb * 4 + g;
        const float* xr = x + (long)n * 75;
        xs[g][c] = xr[c];
        if (c < 11) xs[g][64 + c] = xr[64 + c];
        __syncthreads();
        float h = 0.f;
        #pragma unroll
        for (int k = 0; k < 75; ++k) h += xs[g][k] * W1[k * 64 + c];
        h1p[(long)n * 64 + c] = f2bf(h);
        const int head = c >> 3, lane = c & 7;
        float vs = h * as1[c];
        float vd = h * ad1[c];
        #pragma unroll
        for (int off = 1; off < 8; off <<= 1) {
            vs += __shfl_xor(vs, off, 64);
            vd += __shfl_xor(vd, off, 64);
        }
        if (lane == 0) { a1sh[n * 8 + head] = f2bf(vs); a1d[n * 8 + head] = vd; }
        __syncthreads();   // xs reused next iteration
    }
}

// ---- conv1 gather (persistent, single pass): softmax+agg+elu+proj --------
__global__ __launch_bounds__(256) void k_gat1(
    const int* __restrict__ rowptr, const int* __restrict__ ecol,
    const unsigned short* __restrict__ a1sh, const float* __restrict__ a1d,
    const unsigned short* __restrict__ h1p, const float* __restrict__ bias1,
    const float* __restrict__ wv,
    float2* __restrict__ sg2, float* __restrict__ a2dv)
{
    const int slot = threadIdx.x >> 6;
    const int lane = threadIdx.x & 63;
    const int g = lane >> 3;     // edge-group
    const int l = lane & 7;      // head / channel-block
    const int stride = gridDim.x * 4;

    for (int base = blockIdx.x * 4; base < N_NODES; base += stride) {
        const int dst = base + slot;              // N%4==0 -> always valid
        const int beg = rowptr[dst], end = rowptr[dst + 1];
        const float adh = a1d[(long)dst * 8 + l];

        float acc[8] = {0.f,0.f,0.f,0.f,0.f,0.f,0.f,0.f};
        float den = 0.f;

        int j = beg + g;
        bool v = (j < end);
        int s = v ? ecol[j] : 0;
        unsigned short ab = a1sh[(long)s * 8 + l];
        uint4 pv = *(const uint4*)(h1p + (long)s * 64 + l * 8);

        for (int j0 = beg; j0 < end; j0 += 8) {
            int jn = j + 8;
            bool vn = (jn < end);
            int sn = vn ? ecol[jn] : 0;
            unsigned short abn = a1sh[(long)sn * 8 + l];
            uint4 pvn = *(const uint4*)(h1p + (long)sn * 64 + l * 8);
            float ee = v ? __expf(lrelu(bf2f(ab) + adh)) : 0.f;
            den += ee;
            acc[0] += ee * bflo(pv.x); acc[1] += ee * bfhi(pv.x);
            acc[2] += ee * bflo(pv.y); acc[3] += ee * bfhi(pv.y);
            acc[4] += ee * bflo(pv.z); acc[5] += ee * bfhi(pv.z);
            acc[6] += ee * bflo(pv.w); acc[7] += ee * bfhi(pv.w);
            j = jn; v = vn; s = sn; ab = abn; pv = pvn;
        }
        #pragma unroll
        for (int off = 8; off <= 32; off <<= 1) {
            den += __shfl_xor(den, off, 64);
            #pragma unroll
            for (int k = 0; k < 8; ++k) acc[k] += __shfl_xor(acc[k], off, 64);
        }

        if (g == 0) {
            const float inv = 1.f / den;
            float pg = 0.f, ps = 0.f, pd = 0.f;
            #pragma unroll
            for (int k = 0; k < 8; ++k) {
                float vv = acc[k] * inv + bias1[l * 8 + k];
                vv = vv > 0.f ? vv : (__expf(vv) - 1.f);      // elu -> x2 channel
                pg += vv * wv[l * 8 + k];
                ps += vv * wv[64 + l * 8 + k];
                pd += vv * wv[128 + l * 8 + k];
            }
            #pragma unroll
            for (int off = 1; off < 8; off <<= 1) {
                pg += __shfl_xor(pg, off, 64);
                ps += __shfl_xor(ps, off, 64);
                pd += __shfl_xor(pd, off, 64);
            }
            if (l == 0) { sg2[dst] = make_float2(ps, pg); a2dv[dst] = pd; }
        }
    }
}

// ---- conv2 + pool + linear (persistent, 16-lane subgroups) ---------------
__global__ __launch_bounds__(256) void k_gat2(
    const int* __restrict__ rowptr, const int* __restrict__ ecol,
    const float2* __restrict__ sg2, const float* __restrict__ a2dv,
    const float* __restrict__ wv, const int* __restrict__ batch,
    float* __restrict__ out)
{
    const int lane = threadIdx.x & 63;
    const int sl = lane & 15;                          // lane within subgroup
    const int sgid = ((blockIdx.x * 256 + threadIdx.x) >> 4);  // global subgroup
    const int NS = G2_BLOCKS * 16;                     // total subgroups
    const int per = (N_NODES + NS - 1) / NS;           // nodes per subgroup
    const int n0 = sgid * per;
    const int n1 = min(n0 + per, N_NODES);
    const float bc = wv[192];                          // b2 . Wg

    float accg = 0.f;
    int curg = -1;
    for (int n = n0; n < n1; ++n) {
        const int beg = rowptr[n], end = rowptr[n + 1];
        const float adv = a2dv[n];
        float num = 0.f, den = 0.f;
        for (int j = beg + sl; j < end; j += 16) {
            int s = ecol[j];
            float2 v = sg2[s];                 // {a2s, g2}: 8 B, L2-resident
            float ee = __expf(lrelu(v.x + adv));
            den += ee;
            num += ee * v.y;
        }
        #pragma unroll
        for (int off = 1; off < 16; off <<= 1) {   // stays within 16-lane group
            den += __shfl_xor(den, off, 64);
            num += __shfl_xor(num, off, 64);
        }
        if (sl == 0) {
            int gr = batch[n];
            if (gr != curg) {
                if (curg >= 0) atomAddF(out + curg, accg);
                curg = gr; accg = 0.f;
            }
            accg += num / den + bc;
        }
    }
    if (sl == 0 && curg >= 0) atomAddF(out + curg, accg);
}

extern "C" void kernel_launch(void* const* d_in, const int* in_sizes, int n_in,
                              void* d_out, int out_size, void* d_ws, size_t ws_size,
                              hipStream_t stream) {
    (void)in_sizes; (void)n_in; (void)out_size; (void)ws_size;
    const float* x     = (const float*)d_in[0];
    const int*   ei    = (const int*)d_in[1];
    const int*   batch = (const int*)d_in[2];
    const float* W1    = (const float*)d_in[3];
    const float* as1   = (const float*)d_in[4];
    const float* ad1   = (const float*)d_in[5];
    const float* b1    = (const float*)d_in[6];
    const float* W2    = (const float*)d_in[7];
    const float* as2   = (const float*)d_in[8];
    const float* ad2   = (const float*)d_in[9];
    const float* b2    = (const float*)d_in[10];
    const float* Wg    = (const float*)d_in[11];
    const float* bg    = (const float*)d_in[12];
    float* out = (float*)d_out;

    // ---- workspace layout (16-B aligned chunks; total ~45 MB) ----
    const long N = N_NODES;
    char* p = (char*)d_ws;
    int* rowptr = (int*)p;              p += (N + 4)        * sizeof(int);
    int* bcur   = (int*)p;              p += 512            * sizeof(int);
    int* ecol   = (int*)p;              p += (long)ET       * sizeof(int);
    uint2* gbuf = (uint2*)p;            p += (long)NBUCK * BCAP * sizeof(uint2);
    unsigned short* h1p  = (unsigned short*)p; p += N * 64  * sizeof(unsigned short);
    unsigned short* a1sh = (unsigned short*)p; p += N * 8   * sizeof(unsigned short);
    float* a1d  = (float*)p;            p += N * 8          * sizeof(float);
    float2* sg2 = (float2*)p;           p += N              * sizeof(float2);
    float* a2dv = (float*)p;            p += N              * sizeof(float);
    float* wv   = (float*)p;            p += 256            * sizeof(float);

    // ---- CSR build (bucketed two-pass, high-occupancy) ----
    hipMemsetAsync(bcur, 0, NBUCK * sizeof(int), stream);
    k_binA <<<ABLK, 256, 0, stream>>>(ei, gbuf, bcur);
    k_binB <<<NBUCK, 256, 0, stream>>>(gbuf, bcur, rowptr, ecol);

    // ---- conv1 (+ fused projection to conv2 scalars) ----
    k_wv   <<<3, 256, 0, stream>>>(W2, as2, ad2, Wg, b2, bg, wv, out);
    k_feat1<<<F1_BLOCKS, 256, 0, stream>>>(x, W1, as1, ad1, h1p, a1sh, a1d);
    k_gat1 <<<G1_BLOCKS, 256, 0, stream>>>(rowptr, ecol, a1sh, a1d, h1p, b1, wv, sg2, a2dv);

    // ---- conv2 + pool + linear (scalar form, persistent) ----
    k_gat2 <<<G2_BLOCKS, 256, 0, stream>>>(rowptr, ecol, sg2, a2dv, wv, batch, out);
}

// Round 11
// 311.767 us; speedup vs baseline: 2.6805x; 1.0412x over previous
//
#include <hip/hip_runtime.h>
#include <hip/hip_bf16.h>
#include <math.h>

#define N_NODES 100000
#define N_EDGES 1600000
#define ET (N_EDGES + N_NODES)   // edges + self-loops
#define N_GRAPHS 512
#define NEG_SLOPE 0.2f
#define G1_BLOCKS 2048  // persistent k_gat1 grid
#define G2_BLOCKS 1280  // persistent k_gat2 grid
#define F1_BLOCKS 2048  // persistent feat1 sub-grid (inside k_mid)

// ---- bucketed CSR build params ----
#define BSH 8                                 // 256 nodes per bucket
#define NBUCK ((N_NODES + 255) / 256)         // 391
#define BCAP 5120                             // per-bucket capacity (mean 4352, 12 sigma)
#define ABLK 1024                             // binA sub-grid
#define CHUNK ((ET + ABLK - 1) / ABLK)        // 1661 edges per binA block

__device__ __forceinline__ void atomAddF(float* p, float v) { unsafeAtomicAdd(p, v); }
__device__ __forceinline__ float lrelu(float v) { return v >= 0.f ? v : NEG_SLOPE * v; }

// bf16 helpers (RNE round)
__device__ __forceinline__ unsigned short f2bf(float f) {
    unsigned int u = __float_as_uint(f);
    u += 0x7FFFu + ((u >> 16) & 1u);
    return (unsigned short)(u >> 16);
}
__device__ __forceinline__ float bf2f(unsigned short s) { return __uint_as_float(((unsigned int)s) << 16); }
__device__ __forceinline__ float bflo(unsigned int p) { return __uint_as_float(p << 16); }
__device__ __forceinline__ float bfhi(unsigned int p) { return __uint_as_float(p & 0xFFFF0000u); }

// ============ Launch 1: binA (blocks 0..ABLK-1) + wv/out-init ============
__global__ __launch_bounds__(256) void k_pre(
    const int* __restrict__ ei, uint2* __restrict__ gbuf, int* __restrict__ bcur,
    const float* __restrict__ W2, const float* __restrict__ as2,
    const float* __restrict__ ad2, const float* __restrict__ Wg,
    const float* __restrict__ b2, const float* __restrict__ bg,
    float* __restrict__ wv, float* __restrict__ out)
{
    __shared__ __align__(16) char smem[CHUNK * 8 + NBUCK * 16];
    const int t = threadIdx.x;

    if (blockIdx.x >= ABLK) {
        // ---- wv precompute (block ABLK) + out init (blocks ABLK+1, ABLK+2)
        const int bb = blockIdx.x - ABLK;
        if (bb > 0) {
            int i = (bb - 1) * 256 + t;
            if (i < N_GRAPHS) out[i] = bg[0];
            return;
        }
        if (t < 192) {
            int c = t & 63, which = t >> 6;
            const float* v = (which == 0) ? Wg : ((which == 1) ? as2 : ad2);
            float s = 0.f;
            #pragma unroll
            for (int k = 0; k < 128; ++k) s += W2[c * 128 + k] * v[k];
            wv[which * 64 + c] = s;
        } else if (t == 192) {
            float s = 0.f;
            #pragma unroll
            for (int k = 0; k < 128; ++k) s += b2[k] * Wg[k];
            wv[192] = s;
        }
        return;
    }

    // ---- binA: per-chunk LDS counting sort by bucket ----
    uint2* pairs = (uint2*)smem;                       // CHUNK
    int* hist  = (int*)(smem + CHUNK * 8);             // NBUCK
    int* excl  = hist + NBUCK;
    int* gbase = excl + NBUCK;
    int* cnt2  = gbase + NBUCK;
    const long e0 = (long)blockIdx.x * CHUNK;
    const int  n  = (int)((e0 + CHUNK <= ET) ? CHUNK : (ET - e0));
    for (int i = t; i < NBUCK; i += 256) { hist[i] = 0; cnt2[i] = 0; }
    __syncthreads();
    for (int i = t; i < n; i += 256) {
        long e = e0 + i;
        int dst = (e < N_EDGES) ? ei[N_EDGES + e] : (int)(e - N_EDGES);
        atomicAdd(&hist[dst >> BSH], 1);
    }
    __syncthreads();
    if (t == 0) {
        int acc = 0;
        for (int b = 0; b < NBUCK; ++b) { excl[b] = acc; acc += hist[b]; }
    }
    __syncthreads();
    for (int i = t; i < n; i += 256) {
        long e = e0 + i;
        int src, dst;
        if (e < N_EDGES) { src = ei[e]; dst = ei[N_EDGES + e]; }
        else             { src = dst = (int)(e - N_EDGES); }
        int b = dst >> BSH;
        int pos = excl[b] + atomicAdd(&cnt2[b], 1);
        pairs[pos] = make_uint2((unsigned)src, (unsigned)dst);
    }
    __syncthreads();
    for (int b = t; b < NBUCK; b += 256)
        gbase[b] = hist[b] ? atomicAdd(&bcur[b], hist[b]) : 0;
    __syncthreads();
    for (int i = t; i < n; i += 256) {
        uint2 pr = pairs[i];
        int b = (int)(pr.y >> BSH);
        gbuf[(long)b * BCAP + gbase[b] + (i - excl[b])] = pr;
    }
}

// ============ Launch 2: binB (blocks 0..NBUCK-1) + feat1 (rest) ==========
__global__ __launch_bounds__(256) void k_mid(
    const uint2* __restrict__ gbuf, const int* __restrict__ bcur,
    int* __restrict__ rowptr, int* __restrict__ ecol,
    const float* __restrict__ x, const float* __restrict__ W1,
    const float* __restrict__ as1, const float* __restrict__ ad1,
    unsigned short* __restrict__ h1p, unsigned short* __restrict__ a1sh,
    float* __restrict__ a1d)
{
    __shared__ __align__(16) char smem[4096];
    const int t = threadIdx.x;

    if (blockIdx.x >= NBUCK) {
        // ---- feat1 (persistent over node groups) ----
        float (*xs)[76] = (float (*)[76])smem;      // 4x76 floats = 1216 B
        const int g = t >> 6;
        const int c = t & 63;
        const int vb = blockIdx.x - NBUCK;
        for (int nb = vb; nb < N_NODES / 4; nb += F1_BLOCKS) {
            const int n = nb * 4 + g;
            const float* xr = x + (long)n * 75;
            xs[g][c] = xr[c];
            if (c < 11) xs[g][64 + c] = xr[64 + c];
            __syncthreads();
            float h = 0.f;
            #pragma unroll
            for (int k = 0; k < 75; ++k) h += xs[g][k] * W1[k * 64 + c];
            h1p[(long)n * 64 + c] = f2bf(h);
            const int head = c >> 3, lane = c & 7;
            float vs = h * as1[c];
            float vd = h * ad1[c];
            #pragma unroll
            for (int off = 1; off < 8; off <<= 1) {
                vs += __shfl_xor(vs, off, 64);
                vd += __shfl_xor(vd, off, 64);
            }
            if (lane == 0) { a1sh[n * 8 + head] = f2bf(vs); a1d[n * 8 + head] = vd; }
            __syncthreads();   // xs reused next iteration
        }
        return;
    }

    // ---- binB: per-bucket fine CSR ----
    int* hist = (int*)smem;          // 256
    int* excl = hist + 256;
    int* cnt2 = excl + 256;
    int* red  = cnt2 + 256;
    const int b = blockIdx.x;
    const int cnt  = bcur[b];
    const int d0 = b << BSH;
    const int nloc = (N_NODES - d0 < 256) ? (N_NODES - d0) : 256;

    // inline exclusive prefix: base = sum of bcur[0..b)
    int partial = 0;
    for (int i = t; i < b; i += 256) partial += bcur[i];
    red[t] = partial;
    __syncthreads();
    for (int off = 128; off > 0; off >>= 1) {
        if (t < off) red[t] += red[t + off];
        __syncthreads();
    }
    const int base = red[0];

    if (t < nloc) { hist[t] = 0; cnt2[t] = 0; }
    __syncthreads();
    const uint2* eb = gbuf + (long)b * BCAP;
    for (int i = t; i < cnt; i += 256) atomicAdd(&hist[(int)eb[i].y - d0], 1);
    __syncthreads();
    if (t == 0) {
        int acc = 0;
        for (int k = 0; k < nloc; ++k) { excl[k] = acc; acc += hist[k]; }
    }
    __syncthreads();
    if (t < nloc) rowptr[d0 + t] = base + excl[t];
    if (b == NBUCK - 1 && t == 0) rowptr[N_NODES] = base + cnt;   // == ET
    for (int i = t; i < cnt; i += 256) {
        uint2 pr = eb[i];
        int dl = (int)pr.y - d0;
        int slot = excl[dl] + atomicAdd(&cnt2[dl], 1);
        ecol[base + slot] = (int)pr.x;
    }
}

// ---- conv1 gather (persistent, single pass): softmax+agg+elu+proj --------
__global__ __launch_bounds__(256) void k_gat1(
    const int* __restrict__ rowptr, const int* __restrict__ ecol,
    const unsigned short* __restrict__ a1sh, const float* __restrict__ a1d,
    const unsigned short* __restrict__ h1p, const float* __restrict__ bias1,
    const float* __restrict__ wv,
    float2* __restrict__ sg2, float* __restrict__ a2dv)
{
    const int slot = threadIdx.x >> 6;
    const int lane = threadIdx.x & 63;
    const int g = lane >> 3;     // edge-group
    const int l = lane & 7;      // head / channel-block
    const int stride = gridDim.x * 4;

    for (int base = blockIdx.x * 4; base < N_NODES; base += stride) {
        const int dst = base + slot;              // N%4==0 -> always valid
        const int beg = rowptr[dst], end = rowptr[dst + 1];
        const float adh = a1d[(long)dst * 8 + l];

        float acc[8] = {0.f,0.f,0.f,0.f,0.f,0.f,0.f,0.f};
        float den = 0.f;

        int j = beg + g;
        bool v = (j < end);
        int s = v ? ecol[j] : 0;
        unsigned short ab = a1sh[(long)s * 8 + l];
        uint4 pv = *(const uint4*)(h1p + (long)s * 64 + l * 8);

        for (int j0 = beg; j0 < end; j0 += 8) {
            int jn = j + 8;
            bool vn = (jn < end);
            int sn = vn ? ecol[jn] : 0;
            unsigned short abn = a1sh[(long)sn * 8 + l];
            uint4 pvn = *(const uint4*)(h1p + (long)sn * 64 + l * 8);
            float ee = v ? __expf(lrelu(bf2f(ab) + adh)) : 0.f;
            den += ee;
            acc[0] += ee * bflo(pv.x); acc[1] += ee * bfhi(pv.x);
            acc[2] += ee * bflo(pv.y); acc[3] += ee * bfhi(pv.y);
            acc[4] += ee * bflo(pv.z); acc[5] += ee * bfhi(pv.z);
            acc[6] += ee * bflo(pv.w); acc[7] += ee * bfhi(pv.w);
            j = jn; v = vn; s = sn; ab = abn; pv = pvn;
        }
        #pragma unroll
        for (int off = 8; off <= 32; off <<= 1) {
            den += __shfl_xor(den, off, 64);
            #pragma unroll
            for (int k = 0; k < 8; ++k) acc[k] += __shfl_xor(acc[k], off, 64);
        }

        if (g == 0) {
            const float inv = 1.f / den;
            float pg = 0.f, ps = 0.f, pd = 0.f;
            #pragma unroll
            for (int k = 0; k < 8; ++k) {
                float vv = acc[k] * inv + bias1[l * 8 + k];
                vv = vv > 0.f ? vv : (__expf(vv) - 1.f);      // elu -> x2 channel
                pg += vv * wv[l * 8 + k];
                ps += vv * wv[64 + l * 8 + k];
                pd += vv * wv[128 + l * 8 + k];
            }
            #pragma unroll
            for (int off = 1; off < 8; off <<= 1) {
                pg += __shfl_xor(pg, off, 64);
                ps += __shfl_xor(ps, off, 64);
                pd += __shfl_xor(pd, off, 64);
            }
            if (l == 0) { sg2[dst] = make_float2(ps, pg); a2dv[dst] = pd; }
        }
    }
}

// ---- conv2 + pool + linear (persistent, 16-lane subgroups) ---------------
__global__ __launch_bounds__(256) void k_gat2(
    const int* __restrict__ rowptr, const int* __restrict__ ecol,
    const float2* __restrict__ sg2, const float* __restrict__ a2dv,
    const float* __restrict__ wv, const int* __restrict__ batch,
    float* __restrict__ out)
{
    const int lane = threadIdx.x & 63;
    const int sl = lane & 15;                          // lane within subgroup
    const int sgid = ((blockIdx.x * 256 + threadIdx.x) >> 4);  // global subgroup
    const int NS = G2_BLOCKS * 16;                     // total subgroups
    const int per = (N_NODES + NS - 1) / NS;           // nodes per subgroup
    const int n0 = sgid * per;
    const int n1 = min(n0 + per, N_NODES);
    const float bc = wv[192];                          // b2 . Wg

    float accg = 0.f;
    int curg = -1;
    for (int n = n0; n < n1; ++n) {
        const int beg = rowptr[n], end = rowptr[n + 1];
        const float adv = a2dv[n];
        float num = 0.f, den = 0.f;
        for (int j = beg + sl; j < end; j += 16) {
            int s = ecol[j];
            float2 v = sg2[s];                 // {a2s, g2}: 8 B, L2-resident
            float ee = __expf(lrelu(v.x + adv));
            den += ee;
            num += ee * v.y;
        }
        #pragma unroll
        for (int off = 1; off < 16; off <<= 1) {   // stays within 16-lane group
            den += __shfl_xor(den, off, 64);
            num += __shfl_xor(num, off, 64);
        }
        if (sl == 0) {
            int gr = batch[n];
            if (gr != curg) {
                if (curg >= 0) atomAddF(out + curg, accg);
                curg = gr; accg = 0.f;
            }
            accg += num / den + bc;
        }
    }
    if (sl == 0 && curg >= 0) atomAddF(out + curg, accg);
}

extern "C" void kernel_launch(void* const* d_in, const int* in_sizes, int n_in,
                              void* d_out, int out_size, void* d_ws, size_t ws_size,
                              hipStream_t stream) {
    (void)in_sizes; (void)n_in; (void)out_size; (void)ws_size;
    const float* x     = (const float*)d_in[0];
    const int*   ei    = (const int*)d_in[1];
    const int*   batch = (const int*)d_in[2];
    const float* W1    = (const float*)d_in[3];
    const float* as1   = (const float*)d_in[4];
    const float* ad1   = (const float*)d_in[5];
    const float* b1    = (const float*)d_in[6];
    const float* W2    = (const float*)d_in[7];
    const float* as2   = (const float*)d_in[8];
    const float* ad2   = (const float*)d_in[9];
    const float* b2    = (const float*)d_in[10];
    const float* Wg    = (const float*)d_in[11];
    const float* bg    = (const float*)d_in[12];
    float* out = (float*)d_out;

    // ---- workspace layout (16-B aligned chunks; total ~45 MB) ----
    const long N = N_NODES;
    char* p = (char*)d_ws;
    int* rowptr = (int*)p;              p += (N + 4)        * sizeof(int);
    int* bcur   = (int*)p;              p += 512            * sizeof(int);
    int* ecol   = (int*)p;              p += (long)ET       * sizeof(int);
    uint2* gbuf = (uint2*)p;            p += (long)NBUCK * BCAP * sizeof(uint2);
    unsigned short* h1p  = (unsigned short*)p; p += N * 64  * sizeof(unsigned short);
    unsigned short* a1sh = (unsigned short*)p; p += N * 8   * sizeof(unsigned short);
    float* a1d  = (float*)p;            p += N * 8          * sizeof(float);
    float2* sg2 = (float2*)p;           p += N              * sizeof(float2);
    float* a2dv = (float*)p;            p += N              * sizeof(float);
    float* wv   = (float*)p;            p += 256            * sizeof(float);

    hipMemsetAsync(bcur, 0, NBUCK * sizeof(int), stream);
    // L1: CSR pass A + wv precompute + out init (independent work co-scheduled)
    k_pre <<<ABLK + 3, 256, 0, stream>>>(ei, gbuf, bcur,
                                         W2, as2, ad2, Wg, b2, bg, wv, out);
    // L2: CSR pass B + conv1 features (independent work co-scheduled)
    k_mid <<<NBUCK + F1_BLOCKS, 256, 0, stream>>>(gbuf, bcur, rowptr, ecol,
                                                  x, W1, as1, ad1, h1p, a1sh, a1d);
    // L3: conv1 gather + projection
    k_gat1<<<G1_BLOCKS, 256, 0, stream>>>(rowptr, ecol, a1sh, a1d, h1p, b1, wv, sg2, a2dv);
    // L4: conv2 + pool + linear (scalar form)
    k_gat2<<<G2_BLOCKS, 256, 0, stream>>>(rowptr, ecol, sg2, a2dv, wv, batch, out);
}